// Round 18
// baseline (1526.096 us; speedup 1.0000x reference)
//
#include <hip/hip_runtime.h>

typedef unsigned short u16;
typedef __bf16 bf16;
typedef bf16  bf16x4 __attribute__((ext_vector_type(4)));
typedef bf16  bf16x8 __attribute__((ext_vector_type(8)));
typedef float f32x4  __attribute__((ext_vector_type(4)));

__device__ __forceinline__ u16  f2b(float v) { return __builtin_bit_cast(u16, (bf16)v); }
__device__ __forceinline__ float b2f(u16 b)  { return (float)__builtin_bit_cast(bf16, b); }

// ---------------- dtype probe: flag=1 if float inputs are f32, 0 if bf16 ----------------
__global__ void probe_dtype(const float* xf, int* flag) {
    __shared__ int cnt[256];
    const int tid = threadIdx.x;
    int good = 0;
#pragma unroll
    for (int i = 0; i < 4; ++i) {
        const float a = fabsf(xf[tid * 4 + i]);
        if (a > 9.5e-7f && a < 1.0e6f) good++;   // NaN fails both
    }
    cnt[tid] = good;
    __syncthreads();
    if (tid == 0) { int s = 0; for (int i = 0; i < 256; ++i) s += cnt[i]; *flag = (s > 512) ? 1 : 0; }
}

// ---------------- small-vector convert -> bf16 copy in ws ----------------
__global__ void cvt_vec(const void* in, bf16* out, int n, const int* flag) {
    const int f32 = *flag;
    for (int i = blockIdx.x * 256 + threadIdx.x; i < n; i += gridDim.x * 256)
        out[i] = f32 ? (bf16)(((const float*)in)[i])
                     : __builtin_bit_cast(bf16, ((const u16*)in)[i]);
}

// sum of three vectors (flag dtype) -> bf16
__global__ void sum3_vec(const void* a, const void* b, const void* c, bf16* out, int n, const int* flag) {
    const int f32 = *flag;
    for (int i = blockIdx.x * 256 + threadIdx.x; i < n; i += gridDim.x * 256) {
        float va, vb, vc;
        if (f32) { va = ((const float*)a)[i]; vb = ((const float*)b)[i]; vc = ((const float*)c)[i]; }
        else { va = b2f(((const u16*)a)[i]); vb = b2f(((const u16*)b)[i]); vc = b2f(((const u16*)c)[i]); }
        out[i] = (bf16)(va + vb + vc);
    }
}

__global__ void zfill(bf16* p, int n) {
    for (int i = blockIdx.x * 256 + threadIdx.x; i < n; i += gridDim.x * 256) p[i] = (bf16)0.f;
}

// ---- transpose + convert: in[z][R][C] (flag dtype) -> out[z][C][ostride] bf16 ----
__global__ void transpose_cvt(const void* in, u16* out, size_t base_off, int R, int C, int ostride, const int* flag) {
    __shared__ u16 tile[32][34];
    const int f32 = *flag;
    const int c0 = blockIdx.x * 32, r0 = blockIdx.y * 32;
    const size_t bi = base_off + (size_t)blockIdx.z * R * C;
    const size_t bo = (size_t)blockIdx.z * C * ostride;
    const int tx = threadIdx.x, ty = threadIdx.y;
#pragma unroll
    for (int i = 0; i < 4; ++i) {
        const size_t idx = bi + (size_t)(r0 + ty + i * 8) * C + c0 + tx;
        tile[ty + i * 8][tx] = f32 ? f2b(((const float*)in)[idx]) : ((const u16*)in)[idx];
    }
    __syncthreads();
#pragma unroll
    for (int i = 0; i < 4; ++i)
        out[bo + (size_t)(c0 + ty + i * 8) * ostride + r0 + tx] = tile[tx][ty + i * 8];
}

// ---------------- output transpose: in[z][R][C] bf16 -> out[z][C][R] (flag dtype) ----------------
__global__ void transpose_out(const u16* in, void* out, size_t base_off, int R, int C, const int* flag) {
    __shared__ u16 tile[32][34];
    const int f32 = *flag;
    const int c0 = blockIdx.x * 32, r0 = blockIdx.y * 32;
    const size_t bi = (size_t)blockIdx.z * R * C;
    const size_t bo = base_off + (size_t)blockIdx.z * R * C;
    const int tx = threadIdx.x, ty = threadIdx.y;
#pragma unroll
    for (int i = 0; i < 4; ++i)
        tile[ty + i * 8][tx] = in[bi + (size_t)(r0 + ty + i * 8) * C + c0 + tx];
    __syncthreads();
#pragma unroll
    for (int i = 0; i < 4; ++i) {
        const size_t o = bo + (size_t)(c0 + ty + i * 8) * R + r0 + tx;
        const u16 v = tile[tx][ty + i * 8];
        if (f32) ((float*)out)[o] = b2f(v); else ((u16*)out)[o] = v;
    }
}

// ---------------- global -> LDS async staging (16B/lane) ----------------
__device__ __forceinline__ void gld_lds16(const bf16* g, bf16* l) {
    __builtin_amdgcn_global_load_lds((__attribute__((address_space(1))) void*)g,
                                     (__attribute__((address_space(3))) void*)l,
                                     16, 0, 0);
}

// ---------------- GEMM 256x256, 8 waves, 2-phase dbuf, swizzled LDS (PROVEN R5-R17) ----------------
// MODE 0: C = acc ; MODE 2: C = gelu(acc + bias[n])
template<int MODE>
__global__ __launch_bounds__(512)
void gemm256(const bf16* __restrict__ A, const bf16* __restrict__ BT,
             bf16* C, const bf16* __restrict__ bias, int M, int N, int K)
{
    __shared__ __align__(16) bf16 sm[65536];        // 128 KB
    const int tid = threadIdx.x;

    const int gx = gridDim.x, gy = gridDim.y;
    int lin = blockIdx.y * gx + blockIdx.x;
    const int nwg = gx * gy;
    const int q = nwg >> 3, r8 = nwg & 7;
    const int xcd = lin & 7, idx = lin >> 3;
    lin = (xcd < r8 ? xcd * (q + 1) : r8 * (q + 1) + (xcd - r8) * q) + idx;
    const int bm0 = (lin / gy) * 256;
    const int bn0 = (lin % gy) * 256;

    const int lane = tid & 63, wid = tid >> 6;
    const int wr = wid >> 2, wc = wid & 3;           // 2x4 waves, wave tile 128x64
    const int fr = lane & 15, fg = lane >> 4;
    const int arow = tid >> 3;                       // 0..63
    const int scol = ((tid & 7) ^ (arow & 7)) << 3;  // pre-swizzled source col

    const bf16* Ab = A  + (size_t)(bm0 + arow) * K + scol;
    const bf16* Bb = BT + (size_t)(bn0 + arow) * K + scol;

    bf16* const lA0 = sm;
    bf16* const lA1 = sm + 16384;
    bf16* const lB0 = sm + 32768;
    bf16* const lB1 = sm + 49152;

    f32x4 acc[8][4] = {};
    const int NT = K >> 6;

#pragma unroll
    for (int i = 0; i < 4; ++i) gld_lds16(Ab + (size_t)i * 64 * K, lA0 + i * 4096 + tid * 8);
#pragma unroll
    for (int i = 0; i < 4; ++i) gld_lds16(Bb + (size_t)i * 64 * K, lB0 + i * 4096 + tid * 8);
    __syncthreads();

    const int sw = fr & 7;
    for (int t = 0; t < NT; ++t) {
        if (t + 1 < NT) {
            const int k0 = (t + 1) << 6;
            bf16* la = ((t + 1) & 1) ? lA1 : lA0;
            bf16* lb = ((t + 1) & 1) ? lB1 : lB0;
#pragma unroll
            for (int i = 0; i < 4; ++i) gld_lds16(Ab + k0 + (size_t)i * 64 * K, la + i * 4096 + tid * 8);
#pragma unroll
            for (int i = 0; i < 4; ++i) gld_lds16(Bb + k0 + (size_t)i * 64 * K, lb + i * 4096 + tid * 8);
        }
        const bf16* la = (t & 1) ? lA1 : lA0;
        const bf16* lb = (t & 1) ? lB1 : lB0;
#pragma unroll
        for (int kk = 0; kk < 2; ++kk) {
            const int so = ((((kk << 2) + fg) ^ sw) << 3);
            bf16x8 bfv[4];
#pragma unroll
            for (int n = 0; n < 4; ++n)
                bfv[n] = *(const bf16x8*)&lb[(wc * 64 + n * 16 + fr) * 64 + so];
#pragma unroll
            for (int m = 0; m < 8; ++m) {
                const bf16x8 af = *(const bf16x8*)&la[(wr * 128 + m * 16 + fr) * 64 + so];
#pragma unroll
                for (int n = 0; n < 4; ++n)
                    acc[m][n] = __builtin_amdgcn_mfma_f32_16x16x32_bf16(af, bfv[n], acc[m][n], 0, 0, 0);
            }
        }
        __syncthreads();
    }

    // epilogue: acc (+bias/gelu) -> LDS bf16 [256][256] -> coalesced 16B stores
#pragma unroll
    for (int n = 0; n < 4; ++n) {
        const int col = wc * 64 + n * 16 + fr;
        const float bv = (MODE == 2) ? (float)bias[bn0 + col] : 0.f;
#pragma unroll
        for (int m = 0; m < 8; ++m) {
            const int row0 = wr * 128 + m * 16 + fg * 4;
#pragma unroll
            for (int r = 0; r < 4; ++r) {
                float v = acc[m][n][r];
                if (MODE == 2) { v += bv; v = 0.5f * v * (1.f + erff(v * 0.70710678118654752f)); }
                sm[(row0 + r) * 256 + col] = (bf16)v;
            }
        }
    }
    __syncthreads();
#pragma unroll
    for (int it = 0; it < 16; ++it) {
        const int chunk = it * 512 + tid;
        const int row = chunk >> 5, c8 = (chunk & 31) << 3;
        *(bf16x8*)&C[(size_t)(bm0 + row) * N + bn0 + c8] = *(const bf16x8*)&sm[row * 256 + c8];
    }
}

// ======== GEMM 128x128: SINGLE-buffer m97 2-barrier loop, 32KB LDS (PROVEN R13-R17) ========
// MODE 0: C = acc ; MODE 1: C = acc + bias[n] + add[m,n]
template<int MODE>
__global__ __launch_bounds__(256)
void gemm_bt(const bf16* __restrict__ A, const bf16* __restrict__ BT,
             bf16* C, const bf16* __restrict__ bias,
             const bf16* add, int M, int N, int K)
{
    __shared__ __align__(16) bf16 sm[16384];         // 32 KB: stage A(16KB)+B(16KB); epi: f32 64x128
    const int tid = threadIdx.x;

    const int gx = gridDim.x, gy = gridDim.y;
    int lin = blockIdx.y * gx + blockIdx.x;
    const int nwg = gx * gy;
    const int q = nwg >> 3, r8 = nwg & 7;
    const int xcd = lin & 7, idx = lin >> 3;
    lin = (xcd < r8 ? xcd * (q + 1) : r8 * (q + 1) + (xcd - r8) * q) + idx;
    const int bm0 = (lin / gy) * 128;
    const int bn0 = (lin % gy) * 128;

    const int lane = tid & 63, wid = tid >> 6;
    const int wr = wid >> 1, wc = wid & 1;           // 2x2 waves, wave tile 64x64
    const int fr = lane & 15, fg = lane >> 4;
    const int arow = tid >> 3;                       // 0..31
    const int scol = ((tid & 7) ^ (arow & 7)) << 3;

    const bf16* Ab = A  + (size_t)(bm0 + arow) * K + scol;
    const bf16* Bb = BT + (size_t)(bn0 + arow) * K + scol;

    bf16* const lA = sm;                             // 128x64
    bf16* const lB = sm + 8192;

    f32x4 acc[4][4] = {};
    const int NT = K >> 6;
    const int sw = fr & 7;

    for (int t = 0; t < NT; ++t) {
        __syncthreads();                             // WAR: previous compute reads retired
        const int k0 = t << 6;
#pragma unroll
        for (int i = 0; i < 4; ++i) gld_lds16(Ab + k0 + (size_t)i * 32 * K, lA + i * 2048 + tid * 8);
#pragma unroll
        for (int i = 0; i < 4; ++i) gld_lds16(Bb + k0 + (size_t)i * 32 * K, lB + i * 2048 + tid * 8);
        __syncthreads();                             // RAW: vmcnt drained, stage visible
#pragma unroll
        for (int kk = 0; kk < 2; ++kk) {
            bf16x8 af[4], bfv[4];
#pragma unroll
            for (int m = 0; m < 4; ++m)
                af[m] = *(const bf16x8*)&lA[(wr * 64 + m * 16 + fr) * 64 + ((((kk << 2) + fg) ^ sw) << 3)];
#pragma unroll
            for (int n = 0; n < 4; ++n)
                bfv[n] = *(const bf16x8*)&lB[(wc * 64 + n * 16 + fr) * 64 + ((((kk << 2) + fg) ^ sw) << 3)];
#pragma unroll
            for (int m = 0; m < 4; ++m)
#pragma unroll
                for (int n = 0; n < 4; ++n)
                    acc[m][n] = __builtin_amdgcn_mfma_f32_16x16x32_bf16(af[m], bfv[n], acc[m][n], 0, 0, 0);
        }
    }
    __syncthreads();                                 // all compute reads done before epi reuse

    // ---- epilogue: two 64-row halves via f32 [64][128] tile, barriered ----
    float* lc = (float*)sm;
#pragma unroll
    for (int half = 0; half < 2; ++half) {
        if (wr == half) {                            // wave-uniform branch
#pragma unroll
            for (int n = 0; n < 4; ++n) {
                const int col = wc * 64 + n * 16 + fr;
#pragma unroll
                for (int m = 0; m < 4; ++m)
#pragma unroll
                    for (int r2 = 0; r2 < 4; ++r2)
                        lc[(m * 16 + fg * 4 + r2) * 128 + col] = acc[m][n][r2];
            }
        }
        __syncthreads();                             // stores visible to all waves
#pragma unroll
        for (int i = 0; i < 8; ++i) {
            const int chunk = i * 256 + tid;         // 2048 chunks = 64x128 / 4
            const int row = chunk >> 5, cb = (chunk & 31) * 4;
            const size_t goff = (size_t)(bm0 + half * 64 + row) * N + bn0 + cb;
            const f32x4 v = ((const f32x4*)lc)[chunk];
            bf16x4 o;
            if (MODE == 1) {
                const bf16x4 bv = *(const bf16x4*)&bias[bn0 + cb];
                const bf16x4 av = *(const bf16x4*)&add[goff];
#pragma unroll
                for (int e = 0; e < 4; ++e) o[e] = (bf16)(v[e] + (float)bv[e] + (float)av[e]);
            } else {
#pragma unroll
                for (int e = 0; e < 4; ++e) o[e] = (bf16)v[e];
            }
            *(bf16x4*)&C[goff] = o;
        }
        __syncthreads();                             // reads done before next half overwrites
    }
}

// ---- attention, T=16: one wave per (seq, head); qs = QKV row stride, os = output row stride ----
__global__ __launch_bounds__(256)
void attn16(const bf16* __restrict__ QKV, bf16* __restrict__ O, int tstride, int lastmul, int qs, int os)
{
    const int lane = threadIdx.x & 63;
    const int gw   = (blockIdx.x * 256 + threadIdx.x) >> 6;
    const int head = gw % 12;
    const int seq  = gw / 12;
    const int b    = seq / 48, r2 = seq % 48;
    const int s    = r2 >> 4, last = r2 & 15;
    const int tbase = b * 768 + s * 256 + last * lastmul;
    const int fr = lane & 15, fg = lane >> 4;

    const size_t rowQ = (size_t)(tbase + fr * tstride) * qs + head * 32 + fg * 8;
    const bf16x8 kf = *(const bf16x8*)(QKV + rowQ + 384);
    const bf16x8 qf = *(const bf16x8*)(QKV + rowQ);
    const f32x4 z = {0.f, 0.f, 0.f, 0.f};
    f32x4 S = __builtin_amdgcn_mfma_f32_16x16x32_bf16(kf, qf, z, 0, 0, 0);

    const float sc = 0.17677669529663687f;
    float mx = fmaxf(fmaxf(S[0], S[1]), fmaxf(S[2], S[3]));
    mx = fmaxf(mx, __shfl_xor(mx, 16));
    mx = fmaxf(mx, __shfl_xor(mx, 32));
    float p[4], sum = 0.f;
#pragma unroll
    for (int r = 0; r < 4; ++r) { p[r] = __expf((S[r] - mx) * sc); sum += p[r]; }
    sum += __shfl_xor(sum, 16);
    sum += __shfl_xor(sum, 32);
    const float inv = 1.f / sum;

    bf16x8 pa;
#pragma unroll
    for (int j = 0; j < 8; ++j) {
        const int srcg = 2 * fg + (j >> 2);
        const float v = __shfl(p[j & 3], fr + 16 * (srcg & 3));
        pa[j] = (bf16)(fg < 2 ? v * inv : 0.f);
    }

#pragma unroll
    for (int t = 0; t < 2; ++t) {
        bf16x8 vf;
#pragma unroll
        for (int j = 0; j < 8; ++j) {
            const int key = fg * 8 + j;
            vf[j] = (fg < 2)
                ? QKV[(size_t)(tbase + key * tstride) * qs + 768 + head * 32 + fr + 16 * t]
                : (bf16)0.f;
        }
        f32x4 o = __builtin_amdgcn_mfma_f32_16x16x32_bf16(pa, vf, z, 0, 0, 0);
#pragma unroll
        for (int r = 0; r < 4; ++r)
            O[(size_t)(tbase + (fg * 4 + r) * tstride) * os + head * 32 + fr + 16 * t] = (bf16)o[r];
    }
}

// ---------------- attention, T=3: one thread per (seq, head) ----------------
__global__ __launch_bounds__(256)
void attn3(const bf16* __restrict__ QKV, bf16* __restrict__ O, int qs, int os)
{
    const int t    = blockIdx.x * 256 + threadIdx.x;
    const int head = t % 12;
    const int seq  = t / 12;
    const int b    = seq >> 8, hw = seq & 255;
    const size_t base  = (size_t)(b * 768 + hw) * qs + head * 32;
    const size_t tstep = (size_t)256 * qs;

    float s[3][3] = {};
#pragma unroll
    for (int c = 0; c < 4; ++c) {
        bf16x8 q[3], k[3];
#pragma unroll
        for (int i = 0; i < 3; ++i) {
            q[i] = *(const bf16x8*)(QKV + base + i * tstep + c * 8);
            k[i] = *(const bf16x8*)(QKV + base + i * tstep + 384 + c * 8);
        }
#pragma unroll
        for (int i = 0; i < 3; ++i)
#pragma unroll
            for (int j = 0; j < 3; ++j) {
                float a = 0.f;
#pragma unroll
                for (int e = 0; e < 8; ++e) a += (float)q[i][e] * (float)k[j][e];
                s[i][j] += a;
            }
    }
    const float sc = 0.17677669529663687f;
    float p[3][3];
#pragma unroll
    for (int i = 0; i < 3; ++i) {
        const float mx = fmaxf(s[i][0], fmaxf(s[i][1], s[i][2]));
        float sum = 0.f;
#pragma unroll
        for (int j = 0; j < 3; ++j) { p[i][j] = __expf((s[i][j] - mx) * sc); sum += p[i][j]; }
        const float inv = 1.f / sum;
#pragma unroll
        for (int j = 0; j < 3; ++j) p[i][j] *= inv;
    }
    const size_t obase = (size_t)(b * 768 + hw) * os + head * 32;
#pragma unroll
    for (int c = 0; c < 4; ++c) {
        bf16x8 v[3];
#pragma unroll
        for (int j = 0; j < 3; ++j) v[j] = *(const bf16x8*)(QKV + base + j * tstep + 768 + c * 8);
#pragma unroll
        for (int i = 0; i < 3; ++i) {
            bf16x8 ov;
#pragma unroll
            for (int e = 0; e < 8; ++e)
                ov[e] = (bf16)(p[i][0] * (float)v[0][e] + p[i][1] * (float)v[1][e] + p[i][2] * (float)v[2][e]);
            *(bf16x8*)(O + obase + (size_t)i * 256 * os + c * 8) = ov;
        }
    }
}

// ---------------- LayerNorm over 384, one wave per token ----------------
__global__ __launch_bounds__(256)
void ln_kernel(const bf16* __restrict__ in, bf16* __restrict__ out,
               const bf16* __restrict__ g, const bf16* __restrict__ be, int ntok)
{
    const int w    = (blockIdx.x * 256 + threadIdx.x) >> 6;
    const int lane = threadIdx.x & 63;
    if (w >= ntok) return;
    const bf16* row = in + (size_t)w * 384;
    float x[6], sum = 0.f;
#pragma unroll
    for (int i = 0; i < 6; ++i) { x[i] = (float)row[lane + i * 64]; sum += x[i]; }
#pragma unroll
    for (int o = 32; o >= 1; o >>= 1) sum += __shfl_xor(sum, o);
    const float mu = sum * (1.f / 384.f);
    float vs = 0.f;
#pragma unroll
    for (int i = 0; i < 6; ++i) { const float d = x[i] - mu; vs += d * d; }
#pragma unroll
    for (int o = 32; o >= 1; o >>= 1) vs += __shfl_xor(vs, o);
    const float rstd = rsqrtf(vs * (1.f / 384.f) + 1e-5f);
    bf16* orow = out + (size_t)w * 384;
#pragma unroll
    for (int i = 0; i < 6; ++i)
        orow[lane + i * 64] = (bf16)((x[i] - mu) * rstd * (float)g[lane + i * 64] + (float)be[lane + i * 64]);
}

// ---------------- launch ----------------
extern "C" void kernel_launch(void* const* d_in, const int* in_sizes, int n_in,
                              void* d_out, int out_size, void* d_ws, size_t ws_size,
                              hipStream_t stream)
{
    const void* x = d_in[0];
    const void *Wq[3], *Wkv[3], *Wo[3], *bo[3];
    for (int i = 0; i < 3; ++i) {
        Wq[i]  = d_in[1 + 4 * i];
        Wkv[i] = d_in[2 + 4 * i];
        Wo[i]  = d_in[3 + 4 * i];
        bo[i]  = d_in[4 + 4 * i];
    }
    const void* g1  = d_in[13];
    const void* be1 = d_in[14];
    const void* W1m = d_in[15];
    const void* b1m = d_in[16];
    const void* W2m = d_in[17];
    const void* b2m = d_in[18];
    const void* g2  = d_in[19];
    const void* be2 = d_in[20];

    // ---- workspace layout ----
    char* ws = (char*)d_ws;
    bf16* qkvTp = (bf16*)(ws);                      // [3840][384] per-axis padded QKV weights (i*1280 rows, rows 1152..1279 zero)
    bf16* woTf = (bf16*)(ws + 2949120ull);          // [384][1152] stacked O-proj weights
    bf16* w1mT = (bf16*)(ws + 3833856ull);          // [1536][384]
    bf16* w2mT = (bf16*)(ws + 5013504ull);          // [384][1536]
    bf16 *vboS, *vg1, *vbe1, *vg2, *vbe2, *vb1m, *vb2m;
    {
        char* vp = ws + 6193152ull;
        vboS = (bf16*)(vp);
        vg1  = (bf16*)(vp + 768);        vbe1 = (bf16*)(vp + 1536);
        vg2  = (bf16*)(vp + 2304);       vbe2 = (bf16*)(vp + 3072);
        vb1m = (bf16*)(vp + 3840);       vb2m = (bf16*)(vp + 6912);
    }
    int* dflag = (int*)(ws + 6204416ull);
    const size_t WB = 6553600ull;                   // chunk region base

    // chunk size: NB=32 (4 chunks); live set during QKV/attn ~138MB -> L3-resident
    int NB = 32;
    while (NB > 2) {
        size_t need = WB + (size_t)NB * 768 * (3 * 384 + 1152 + 1280 + 1536) * 2;
        if (need <= ws_size) break;
        NB >>= 1;
    }
    const int Tc = NB * 768;
    const size_t tokB = (size_t)Tc * 384 * 2;
    bf16* Xc    = (bf16*)(ws + WB);
    bf16* ABc   = (bf16*)(ws + WB + tokB);
    bf16* T1c   = (bf16*)(ws + WB + 2 * tokB);
    bf16* ATOc  = (bf16*)(ws + WB + 3 * tokB);      // Tc x 1152 (3 axes side by side)
    bf16* QKVc  = (bf16*)(ws + WB + 6 * tokB);      // Tc x 1280 (one axis, padded stride)
    bf16* BIGc  = (bf16*)(ws + WB + 6 * tokB + (size_t)Tc * 1280 * 2);  // Tc x 1536 (MLP hidden)

    // ---- dtype probe + conversions ----
    probe_dtype<<<1, 256, 0, stream>>>((const float*)x, dflag);
    sum3_vec<<<2, 256, 0, stream>>>(bo[0], bo[1], bo[2], vboS, 384, dflag);
    cvt_vec<<<2, 256, 0, stream>>>(g1,  vg1,  384,  dflag);
    cvt_vec<<<2, 256, 0, stream>>>(be1, vbe1, 384,  dflag);
    cvt_vec<<<2, 256, 0, stream>>>(g2,  vg2,  384,  dflag);
    cvt_vec<<<2, 256, 0, stream>>>(be2, vbe2, 384,  dflag);
    cvt_vec<<<6, 256, 0, stream>>>(b1m, vb1m, 1536, dflag);
    cvt_vec<<<2, 256, 0, stream>>>(b2m, vb2m, 384,  dflag);
    // zero the pad weight rows (128 rows x 384 per axis)
    for (int i = 0; i < 3; ++i)
        zfill<<<48, 256, 0, stream>>>(qkvTp + ((size_t)i * 1280 + 1152) * 384, 128 * 384);

    const dim3 tb(32, 8);
    for (int i = 0; i < 3; ++i) {
        transpose_cvt<<<dim3(12, 12, 1), tb, 0, stream>>>(Wq[i],  (u16*)(qkvTp + (size_t)(i * 1280) * 384),       0, 384, 384, 384, dflag);
        transpose_cvt<<<dim3(24, 12, 1), tb, 0, stream>>>(Wkv[i], (u16*)(qkvTp + (size_t)(i * 1280 + 384) * 384), 0, 384, 768, 384, dflag);
        transpose_cvt<<<dim3(12, 12, 1), tb, 0, stream>>>(Wo[i],  (u16*)(woTf + i * 384),                         0, 384, 384, 1152, dflag);
    }
    transpose_cvt<<<dim3(48, 12, 1), tb, 0, stream>>>(W1m, (u16*)w1mT, 0, 384, 1536, 384,  dflag);
    transpose_cvt<<<dim3(12, 48, 1), tb, 0, stream>>>(W2m, (u16*)w2mT, 0, 1536, 384, 1536, dflag);

    for (int b0 = 0; b0 < 128; b0 += NB) {
        const size_t xoff = (size_t)b0 * 384 * 768;
        transpose_cvt<<<dim3(24, 12, NB), tb, 0, stream>>>(x, (u16*)Xc, xoff, 384, 768, 384, dflag);

        // per-axis QKV on the faster 256-tile engine (N padded 1152->1280), then attention
        for (int i = 0; i < 3; ++i) {
            gemm256<0><<<dim3(Tc / 256, 5), 512, 0, stream>>>(Xc, qkvTp + (size_t)(i * 1280) * 384,
                                                              QKVc, nullptr, Tc, 1280, 384);
            if (i == 0)      attn3 <<<NB * 12,  256, 0, stream>>>(QKVc, ATOc,              1280, 1152);
            else if (i == 1) attn16<<<NB * 144, 256, 0, stream>>>(QKVc, ATOc + 384, 16, 1, 1280, 1152);
            else             attn16<<<NB * 144, 256, 0, stream>>>(QKVc, ATOc + 768, 1, 16, 1280, 1152);
        }

        // fused O-projection: sum over 3 axes in one K=1152 GEMM (+ Sum(bo) + residual Xc)
        gemm_bt<1><<<dim3(Tc / 128, 3), 256, 0, stream>>>(ATOc, woTf, ABc, vboS, Xc, Tc, 384, 1152);

        ln_kernel<<<Tc / 4, 256, 0, stream>>>(ABc, T1c, vg1, vbe1, Tc);
        gemm256<2><<<dim3(Tc / 256, 6), 512, 0, stream>>>(T1c, w1mT, BIGc, vb1m, Tc, 1536, 384);
        gemm_bt<1><<<dim3(Tc / 128, 3), 256, 0, stream>>>(BIGc, w2mT, ABc, vb2m, T1c, Tc, 384, 1536);
        ln_kernel<<<Tc / 4, 256, 0, stream>>>(ABc, Xc, vg2, vbe2, Tc);
        transpose_out<<<dim3(12, 24, NB), tb, 0, stream>>>((const u16*)Xc, d_out, xoff, 768, 384, dflag);
    }
}

// Round 19
// 1515.829 us; speedup vs baseline: 1.0068x; 1.0068x over previous
//
#include <hip/hip_runtime.h>

typedef unsigned short u16;
typedef __bf16 bf16;
typedef bf16  bf16x4 __attribute__((ext_vector_type(4)));
typedef bf16  bf16x8 __attribute__((ext_vector_type(8)));
typedef float f32x4  __attribute__((ext_vector_type(4)));

__device__ __forceinline__ u16  f2b(float v) { return __builtin_bit_cast(u16, (bf16)v); }
__device__ __forceinline__ float b2f(u16 b)  { return (float)__builtin_bit_cast(bf16, b); }

// ---------------- dtype probe: flag=1 if float inputs are f32, 0 if bf16 ----------------
__global__ void probe_dtype(const float* xf, int* flag) {
    __shared__ int cnt[256];
    const int tid = threadIdx.x;
    int good = 0;
#pragma unroll
    for (int i = 0; i < 4; ++i) {
        const float a = fabsf(xf[tid * 4 + i]);
        if (a > 9.5e-7f && a < 1.0e6f) good++;   // NaN fails both
    }
    cnt[tid] = good;
    __syncthreads();
    if (tid == 0) { int s = 0; for (int i = 0; i < 256; ++i) s += cnt[i]; *flag = (s > 512) ? 1 : 0; }
}

// ---------------- small-vector convert -> bf16 copy in ws ----------------
__global__ void cvt_vec(const void* in, bf16* out, int n, const int* flag) {
    const int f32 = *flag;
    for (int i = blockIdx.x * 256 + threadIdx.x; i < n; i += gridDim.x * 256)
        out[i] = f32 ? (bf16)(((const float*)in)[i])
                     : __builtin_bit_cast(bf16, ((const u16*)in)[i]);
}

// sum of three vectors (flag dtype) -> bf16
__global__ void sum3_vec(const void* a, const void* b, const void* c, bf16* out, int n, const int* flag) {
    const int f32 = *flag;
    for (int i = blockIdx.x * 256 + threadIdx.x; i < n; i += gridDim.x * 256) {
        float va, vb, vc;
        if (f32) { va = ((const float*)a)[i]; vb = ((const float*)b)[i]; vc = ((const float*)c)[i]; }
        else { va = b2f(((const u16*)a)[i]); vb = b2f(((const u16*)b)[i]); vc = b2f(((const u16*)c)[i]); }
        out[i] = (bf16)(va + vb + vc);
    }
}

// ---- transpose + convert: in[z][R][C] (flag dtype) -> out[z][C][ostride] bf16 ----
__global__ void transpose_cvt(const void* in, u16* out, size_t base_off, int R, int C, int ostride, const int* flag) {
    __shared__ u16 tile[32][34];
    const int f32 = *flag;
    const int c0 = blockIdx.x * 32, r0 = blockIdx.y * 32;
    const size_t bi = base_off + (size_t)blockIdx.z * R * C;
    const size_t bo = (size_t)blockIdx.z * C * ostride;
    const int tx = threadIdx.x, ty = threadIdx.y;
#pragma unroll
    for (int i = 0; i < 4; ++i) {
        const size_t idx = bi + (size_t)(r0 + ty + i * 8) * C + c0 + tx;
        tile[ty + i * 8][tx] = f32 ? f2b(((const float*)in)[idx]) : ((const u16*)in)[idx];
    }
    __syncthreads();
#pragma unroll
    for (int i = 0; i < 4; ++i)
        out[bo + (size_t)(c0 + ty + i * 8) * ostride + r0 + tx] = tile[tx][ty + i * 8];
}

// ---------------- output transpose: in[z][R][C] bf16 -> out[z][C][R] (flag dtype) ----------------
__global__ void transpose_out(const u16* in, void* out, size_t base_off, int R, int C, const int* flag) {
    __shared__ u16 tile[32][34];
    const int f32 = *flag;
    const int c0 = blockIdx.x * 32, r0 = blockIdx.y * 32;
    const size_t bi = (size_t)blockIdx.z * R * C;
    const size_t bo = base_off + (size_t)blockIdx.z * R * C;
    const int tx = threadIdx.x, ty = threadIdx.y;
#pragma unroll
    for (int i = 0; i < 4; ++i)
        tile[ty + i * 8][tx] = in[bi + (size_t)(r0 + ty + i * 8) * C + c0 + tx];
    __syncthreads();
#pragma unroll
    for (int i = 0; i < 4; ++i) {
        const size_t o = bo + (size_t)(c0 + ty + i * 8) * R + r0 + tx;
        const u16 v = tile[tx][ty + i * 8];
        if (f32) ((float*)out)[o] = b2f(v); else ((u16*)out)[o] = v;
    }
}

// ---------------- global -> LDS async staging (16B/lane) ----------------
__device__ __forceinline__ void gld_lds16(const bf16* g, bf16* l) {
    __builtin_amdgcn_global_load_lds((__attribute__((address_space(1))) void*)g,
                                     (__attribute__((address_space(3))) void*)l,
                                     16, 0, 0);
}

// ---------------- GEMM 256x256, 8 waves, 2-phase dbuf, swizzled LDS (PROVEN R5-R17) ----------------
// MODE 0: C = acc ; MODE 2: C = gelu(acc + bias[n])
template<int MODE>
__global__ __launch_bounds__(512)
void gemm256(const bf16* __restrict__ A, const bf16* __restrict__ BT,
             bf16* C, const bf16* __restrict__ bias, int M, int N, int K)
{
    __shared__ __align__(16) bf16 sm[65536];        // 128 KB
    const int tid = threadIdx.x;

    const int gx = gridDim.x, gy = gridDim.y;
    int lin = blockIdx.y * gx + blockIdx.x;
    const int nwg = gx * gy;
    const int q = nwg >> 3, r8 = nwg & 7;
    const int xcd = lin & 7, idx = lin >> 3;
    lin = (xcd < r8 ? xcd * (q + 1) : r8 * (q + 1) + (xcd - r8) * q) + idx;
    const int bm0 = (lin / gy) * 256;
    const int bn0 = (lin % gy) * 256;

    const int lane = tid & 63, wid = tid >> 6;
    const int wr = wid >> 2, wc = wid & 3;           // 2x4 waves, wave tile 128x64
    const int fr = lane & 15, fg = lane >> 4;
    const int arow = tid >> 3;                       // 0..63
    const int scol = ((tid & 7) ^ (arow & 7)) << 3;  // pre-swizzled source col

    const bf16* Ab = A  + (size_t)(bm0 + arow) * K + scol;
    const bf16* Bb = BT + (size_t)(bn0 + arow) * K + scol;

    bf16* const lA0 = sm;
    bf16* const lA1 = sm + 16384;
    bf16* const lB0 = sm + 32768;
    bf16* const lB1 = sm + 49152;

    f32x4 acc[8][4] = {};
    const int NT = K >> 6;

#pragma unroll
    for (int i = 0; i < 4; ++i) gld_lds16(Ab + (size_t)i * 64 * K, lA0 + i * 4096 + tid * 8);
#pragma unroll
    for (int i = 0; i < 4; ++i) gld_lds16(Bb + (size_t)i * 64 * K, lB0 + i * 4096 + tid * 8);
    __syncthreads();

    const int sw = fr & 7;
    for (int t = 0; t < NT; ++t) {
        if (t + 1 < NT) {
            const int k0 = (t + 1) << 6;
            bf16* la = ((t + 1) & 1) ? lA1 : lA0;
            bf16* lb = ((t + 1) & 1) ? lB1 : lB0;
#pragma unroll
            for (int i = 0; i < 4; ++i) gld_lds16(Ab + k0 + (size_t)i * 64 * K, la + i * 4096 + tid * 8);
#pragma unroll
            for (int i = 0; i < 4; ++i) gld_lds16(Bb + k0 + (size_t)i * 64 * K, lb + i * 4096 + tid * 8);
        }
        const bf16* la = (t & 1) ? lA1 : lA0;
        const bf16* lb = (t & 1) ? lB1 : lB0;
#pragma unroll
        for (int kk = 0; kk < 2; ++kk) {
            const int so = ((((kk << 2) + fg) ^ sw) << 3);
            bf16x8 bfv[4];
#pragma unroll
            for (int n = 0; n < 4; ++n)
                bfv[n] = *(const bf16x8*)&lb[(wc * 64 + n * 16 + fr) * 64 + so];
#pragma unroll
            for (int m = 0; m < 8; ++m) {
                const bf16x8 af = *(const bf16x8*)&la[(wr * 128 + m * 16 + fr) * 64 + so];
#pragma unroll
                for (int n = 0; n < 4; ++n)
                    acc[m][n] = __builtin_amdgcn_mfma_f32_16x16x32_bf16(af, bfv[n], acc[m][n], 0, 0, 0);
            }
        }
        __syncthreads();
    }

    // epilogue: acc (+bias/gelu) -> LDS bf16 [256][256] -> coalesced 16B stores
#pragma unroll
    for (int n = 0; n < 4; ++n) {
        const int col = wc * 64 + n * 16 + fr;
        const float bv = (MODE == 2) ? (float)bias[bn0 + col] : 0.f;
#pragma unroll
        for (int m = 0; m < 8; ++m) {
            const int row0 = wr * 128 + m * 16 + fg * 4;
#pragma unroll
            for (int r = 0; r < 4; ++r) {
                float v = acc[m][n][r];
                if (MODE == 2) { v += bv; v = 0.5f * v * (1.f + erff(v * 0.70710678118654752f)); }
                sm[(row0 + r) * 256 + col] = (bf16)v;
            }
        }
    }
    __syncthreads();
#pragma unroll
    for (int it = 0; it < 16; ++it) {
        const int chunk = it * 512 + tid;
        const int row = chunk >> 5, c8 = (chunk & 31) << 3;
        *(bf16x8*)&C[(size_t)(bm0 + row) * N + bn0 + c8] = *(const bf16x8*)&sm[row * 256 + c8];
    }
}

// ======== GEMM 128x128: SINGLE-buffer m97 2-barrier loop, 32KB LDS (PROVEN R13-R17) ========
// MODE 0: C = acc ; MODE 1: C = acc + bias[n] + add[m,n]
template<int MODE>
__global__ __launch_bounds__(256)
void gemm_bt(const bf16* __restrict__ A, const bf16* __restrict__ BT,
             bf16* C, const bf16* __restrict__ bias,
             const bf16* add, int M, int N, int K)
{
    __shared__ __align__(16) bf16 sm[16384];         // 32 KB: stage A(16KB)+B(16KB); epi: f32 64x128
    const int tid = threadIdx.x;

    const int gx = gridDim.x, gy = gridDim.y;
    int lin = blockIdx.y * gx + blockIdx.x;
    const int nwg = gx * gy;
    const int q = nwg >> 3, r8 = nwg & 7;
    const int xcd = lin & 7, idx = lin >> 3;
    lin = (xcd < r8 ? xcd * (q + 1) : r8 * (q + 1) + (xcd - r8) * q) + idx;
    const int bm0 = (lin / gy) * 128;
    const int bn0 = (lin % gy) * 128;

    const int lane = tid & 63, wid = tid >> 6;
    const int wr = wid >> 1, wc = wid & 1;           // 2x2 waves, wave tile 64x64
    const int fr = lane & 15, fg = lane >> 4;
    const int arow = tid >> 3;                       // 0..31
    const int scol = ((tid & 7) ^ (arow & 7)) << 3;

    const bf16* Ab = A  + (size_t)(bm0 + arow) * K + scol;
    const bf16* Bb = BT + (size_t)(bn0 + arow) * K + scol;

    bf16* const lA = sm;                             // 128x64
    bf16* const lB = sm + 8192;

    f32x4 acc[4][4] = {};
    const int NT = K >> 6;
    const int sw = fr & 7;

    for (int t = 0; t < NT; ++t) {
        __syncthreads();                             // WAR: previous compute reads retired
        const int k0 = t << 6;
#pragma unroll
        for (int i = 0; i < 4; ++i) gld_lds16(Ab + k0 + (size_t)i * 32 * K, lA + i * 2048 + tid * 8);
#pragma unroll
        for (int i = 0; i < 4; ++i) gld_lds16(Bb + k0 + (size_t)i * 32 * K, lB + i * 2048 + tid * 8);
        __syncthreads();                             // RAW: vmcnt drained, stage visible
#pragma unroll
        for (int kk = 0; kk < 2; ++kk) {
            bf16x8 af[4], bfv[4];
#pragma unroll
            for (int m = 0; m < 4; ++m)
                af[m] = *(const bf16x8*)&lA[(wr * 64 + m * 16 + fr) * 64 + ((((kk << 2) + fg) ^ sw) << 3)];
#pragma unroll
            for (int n = 0; n < 4; ++n)
                bfv[n] = *(const bf16x8*)&lB[(wc * 64 + n * 16 + fr) * 64 + ((((kk << 2) + fg) ^ sw) << 3)];
#pragma unroll
            for (int m = 0; m < 4; ++m)
#pragma unroll
                for (int n = 0; n < 4; ++n)
                    acc[m][n] = __builtin_amdgcn_mfma_f32_16x16x32_bf16(af[m], bfv[n], acc[m][n], 0, 0, 0);
        }
    }
    __syncthreads();                                 // all compute reads done before epi reuse

    // ---- epilogue: two 64-row halves via f32 [64][128] tile, barriered ----
    float* lc = (float*)sm;
#pragma unroll
    for (int half = 0; half < 2; ++half) {
        if (wr == half) {                            // wave-uniform branch
#pragma unroll
            for (int n = 0; n < 4; ++n) {
                const int col = wc * 64 + n * 16 + fr;
#pragma unroll
                for (int m = 0; m < 4; ++m)
#pragma unroll
                    for (int r2 = 0; r2 < 4; ++r2)
                        lc[(m * 16 + fg * 4 + r2) * 128 + col] = acc[m][n][r2];
            }
        }
        __syncthreads();                             // stores visible to all waves
#pragma unroll
        for (int i = 0; i < 8; ++i) {
            const int chunk = i * 256 + tid;         // 2048 chunks = 64x128 / 4
            const int row = chunk >> 5, cb = (chunk & 31) * 4;
            const size_t goff = (size_t)(bm0 + half * 64 + row) * N + bn0 + cb;
            const f32x4 v = ((const f32x4*)lc)[chunk];
            bf16x4 o;
            if (MODE == 1) {
                const bf16x4 bv = *(const bf16x4*)&bias[bn0 + cb];
                const bf16x4 av = *(const bf16x4*)&add[goff];
#pragma unroll
                for (int e = 0; e < 4; ++e) o[e] = (bf16)(v[e] + (float)bv[e] + (float)av[e]);
            } else {
#pragma unroll
                for (int e = 0; e < 4; ++e) o[e] = (bf16)v[e];
            }
            *(bf16x4*)&C[goff] = o;
        }
        __syncthreads();                             // reads done before next half overwrites
    }
}

// ---- attention, T=16: one wave per (seq, head); qs = QKV row stride, os = output row stride ----
__global__ __launch_bounds__(256)
void attn16(const bf16* __restrict__ QKV, bf16* __restrict__ O, int tstride, int lastmul, int qs, int os)
{
    const int lane = threadIdx.x & 63;
    const int gw   = (blockIdx.x * 256 + threadIdx.x) >> 6;
    const int head = gw % 12;
    const int seq  = gw / 12;
    const int b    = seq / 48, r2 = seq % 48;
    const int s    = r2 >> 4, last = r2 & 15;
    const int tbase = b * 768 + s * 256 + last * lastmul;
    const int fr = lane & 15, fg = lane >> 4;

    const size_t rowQ = (size_t)(tbase + fr * tstride) * qs + head * 32 + fg * 8;
    const bf16x8 kf = *(const bf16x8*)(QKV + rowQ + 384);
    const bf16x8 qf = *(const bf16x8*)(QKV + rowQ);
    const f32x4 z = {0.f, 0.f, 0.f, 0.f};
    f32x4 S = __builtin_amdgcn_mfma_f32_16x16x32_bf16(kf, qf, z, 0, 0, 0);

    const float sc = 0.17677669529663687f;
    float mx = fmaxf(fmaxf(S[0], S[1]), fmaxf(S[2], S[3]));
    mx = fmaxf(mx, __shfl_xor(mx, 16));
    mx = fmaxf(mx, __shfl_xor(mx, 32));
    float p[4], sum = 0.f;
#pragma unroll
    for (int r = 0; r < 4; ++r) { p[r] = __expf((S[r] - mx) * sc); sum += p[r]; }
    sum += __shfl_xor(sum, 16);
    sum += __shfl_xor(sum, 32);
    const float inv = 1.f / sum;

    bf16x8 pa;
#pragma unroll
    for (int j = 0; j < 8; ++j) {
        const int srcg = 2 * fg + (j >> 2);
        const float v = __shfl(p[j & 3], fr + 16 * (srcg & 3));
        pa[j] = (bf16)(fg < 2 ? v * inv : 0.f);
    }

#pragma unroll
    for (int t = 0; t < 2; ++t) {
        bf16x8 vf;
#pragma unroll
        for (int j = 0; j < 8; ++j) {
            const int key = fg * 8 + j;
            vf[j] = (fg < 2)
                ? QKV[(size_t)(tbase + key * tstride) * qs + 768 + head * 32 + fr + 16 * t]
                : (bf16)0.f;
        }
        f32x4 o = __builtin_amdgcn_mfma_f32_16x16x32_bf16(pa, vf, z, 0, 0, 0);
#pragma unroll
        for (int r = 0; r < 4; ++r)
            O[(size_t)(tbase + (fg * 4 + r) * tstride) * os + head * 32 + fr + 16 * t] = (bf16)o[r];
    }
}

// ---------------- attention, T=3: one thread per (seq, head) ----------------
__global__ __launch_bounds__(256)
void attn3(const bf16* __restrict__ QKV, bf16* __restrict__ O, int qs, int os)
{
    const int t    = blockIdx.x * 256 + threadIdx.x;
    const int head = t % 12;
    const int seq  = t / 12;
    const int b    = seq >> 8, hw = seq & 255;
    const size_t base  = (size_t)(b * 768 + hw) * qs + head * 32;
    const size_t tstep = (size_t)256 * qs;

    float s[3][3] = {};
#pragma unroll
    for (int c = 0; c < 4; ++c) {
        bf16x8 q[3], k[3];
#pragma unroll
        for (int i = 0; i < 3; ++i) {
            q[i] = *(const bf16x8*)(QKV + base + i * tstep + c * 8);
            k[i] = *(const bf16x8*)(QKV + base + i * tstep + 384 + c * 8);
        }
#pragma unroll
        for (int i = 0; i < 3; ++i)
#pragma unroll
            for (int j = 0; j < 3; ++j) {
                float a = 0.f;
#pragma unroll
                for (int e = 0; e < 8; ++e) a += (float)q[i][e] * (float)k[j][e];
                s[i][j] += a;
            }
    }
    const float sc = 0.17677669529663687f;
    float p[3][3];
#pragma unroll
    for (int i = 0; i < 3; ++i) {
        const float mx = fmaxf(s[i][0], fmaxf(s[i][1], s[i][2]));
        float sum = 0.f;
#pragma unroll
        for (int j = 0; j < 3; ++j) { p[i][j] = __expf((s[i][j] - mx) * sc); sum += p[i][j]; }
        const float inv = 1.f / sum;
#pragma unroll
        for (int j = 0; j < 3; ++j) p[i][j] *= inv;
    }
    const size_t obase = (size_t)(b * 768 + hw) * os + head * 32;
#pragma unroll
    for (int c = 0; c < 4; ++c) {
        bf16x8 v[3];
#pragma unroll
        for (int j = 0; j < 3; ++j) v[j] = *(const bf16x8*)(QKV + base + j * tstep + 768 + c * 8);
#pragma unroll
        for (int i = 0; i < 3; ++i) {
            bf16x8 ov;
#pragma unroll
            for (int e = 0; e < 8; ++e)
                ov[e] = (bf16)(p[i][0] * (float)v[0][e] + p[i][1] * (float)v[1][e] + p[i][2] * (float)v[2][e]);
            *(bf16x8*)(O + obase + (size_t)i * 256 * os + c * 8) = ov;
        }
    }
}

// ---------------- LayerNorm over 384, one wave per token ----------------
__global__ __launch_bounds__(256)
void ln_kernel(const bf16* __restrict__ in, bf16* __restrict__ out,
               const bf16* __restrict__ g, const bf16* __restrict__ be, int ntok)
{
    const int w    = (blockIdx.x * 256 + threadIdx.x) >> 6;
    const int lane = threadIdx.x & 63;
    if (w >= ntok) return;
    const bf16* row = in + (size_t)w * 384;
    float x[6], sum = 0.f;
#pragma unroll
    for (int i = 0; i < 6; ++i) { x[i] = (float)row[lane + i * 64]; sum += x[i]; }
#pragma unroll
    for (int o = 32; o >= 1; o >>= 1) sum += __shfl_xor(sum, o);
    const float mu = sum * (1.f / 384.f);
    float vs = 0.f;
#pragma unroll
    for (int i = 0; i < 6; ++i) { const float d = x[i] - mu; vs += d * d; }
#pragma unroll
    for (int o = 32; o >= 1; o >>= 1) vs += __shfl_xor(vs, o);
    const float rstd = rsqrtf(vs * (1.f / 384.f) + 1e-5f);
    bf16* orow = out + (size_t)w * 384;
#pragma unroll
    for (int i = 0; i < 6; ++i)
        orow[lane + i * 64] = (bf16)((x[i] - mu) * rstd * (float)g[lane + i * 64] + (float)be[lane + i * 64]);
}

// ---------------- launch ----------------
extern "C" void kernel_launch(void* const* d_in, const int* in_sizes, int n_in,
                              void* d_out, int out_size, void* d_ws, size_t ws_size,
                              hipStream_t stream)
{
    const void* x = d_in[0];
    const void *Wq[3], *Wkv[3], *Wo[3], *bo[3];
    for (int i = 0; i < 3; ++i) {
        Wq[i]  = d_in[1 + 4 * i];
        Wkv[i] = d_in[2 + 4 * i];
        Wo[i]  = d_in[3 + 4 * i];
        bo[i]  = d_in[4 + 4 * i];
    }
    const void* g1  = d_in[13];
    const void* be1 = d_in[14];
    const void* W1m = d_in[15];
    const void* b1m = d_in[16];
    const void* W2m = d_in[17];
    const void* b2m = d_in[18];
    const void* g2  = d_in[19];
    const void* be2 = d_in[20];

    // ---- workspace layout ----
    char* ws = (char*)d_ws;
    bf16* qkvT = (bf16*)(ws);                       // [3456][384] per-axis QKV weights (i*1152 rows)
    bf16* woTf = (bf16*)(ws + 2654208ull);          // [384][1152] stacked O-proj weights
    bf16* w1mT = (bf16*)(ws + 3538944ull);          // [1536][384]
    bf16* w2mT = (bf16*)(ws + 4718592ull);          // [384][1536]
    bf16 *vboS, *vg1, *vbe1, *vg2, *vbe2, *vb1m, *vb2m;
    {
        char* vp = ws + 5898240ull;
        vboS = (bf16*)(vp);
        vg1  = (bf16*)(vp + 768);        vbe1 = (bf16*)(vp + 1536);
        vg2  = (bf16*)(vp + 2304);       vbe2 = (bf16*)(vp + 3072);
        vb1m = (bf16*)(vp + 3840);       vb2m = (bf16*)(vp + 6912);
    }
    int* dflag = (int*)(ws + 5909504ull);
    const size_t WB = 6553600ull;                   // chunk region base

    // chunk size: NB=32 (4 chunks); live set during QKV/attn ~132MB -> L3-resident
    int NB = 32;
    while (NB > 2) {
        size_t need = WB + (size_t)NB * 768 * (3 * 384 + 2 * 1152 + 1536) * 2;
        if (need <= ws_size) break;
        NB >>= 1;
    }
    const int Tc = NB * 768;
    const size_t tokB = (size_t)Tc * 384 * 2;
    bf16* Xc    = (bf16*)(ws + WB);
    bf16* ABc   = (bf16*)(ws + WB + tokB);
    bf16* T1c   = (bf16*)(ws + WB + 2 * tokB);
    bf16* ATOc  = (bf16*)(ws + WB + 3 * tokB);      // Tc x 1152 (3 axes side by side)
    bf16* QKVc  = (bf16*)(ws + WB + 6 * tokB);      // Tc x 1152 (one axis at a time)
    bf16* BIGc  = (bf16*)(ws + WB + 9 * tokB);      // Tc x 1536 (MLP hidden)

    // ---- dtype probe + conversions ----
    probe_dtype<<<1, 256, 0, stream>>>((const float*)x, dflag);
    sum3_vec<<<2, 256, 0, stream>>>(bo[0], bo[1], bo[2], vboS, 384, dflag);
    cvt_vec<<<2, 256, 0, stream>>>(g1,  vg1,  384,  dflag);
    cvt_vec<<<2, 256, 0, stream>>>(be1, vbe1, 384,  dflag);
    cvt_vec<<<2, 256, 0, stream>>>(g2,  vg2,  384,  dflag);
    cvt_vec<<<2, 256, 0, stream>>>(be2, vbe2, 384,  dflag);
    cvt_vec<<<6, 256, 0, stream>>>(b1m, vb1m, 1536, dflag);
    cvt_vec<<<2, 256, 0, stream>>>(b2m, vb2m, 384,  dflag);

    const dim3 tb(32, 8);
    for (int i = 0; i < 3; ++i) {
        transpose_cvt<<<dim3(12, 12, 1), tb, 0, stream>>>(Wq[i],  (u16*)(qkvT + (size_t)(i * 1152) * 384),       0, 384, 384, 384, dflag);
        transpose_cvt<<<dim3(24, 12, 1), tb, 0, stream>>>(Wkv[i], (u16*)(qkvT + (size_t)(i * 1152 + 384) * 384), 0, 384, 768, 384, dflag);
        transpose_cvt<<<dim3(12, 12, 1), tb, 0, stream>>>(Wo[i],  (u16*)(woTf + i * 384),                        0, 384, 384, 1152, dflag);
    }
    transpose_cvt<<<dim3(48, 12, 1), tb, 0, stream>>>(W1m, (u16*)w1mT, 0, 384, 1536, 384,  dflag);
    transpose_cvt<<<dim3(12, 48, 1), tb, 0, stream>>>(W2m, (u16*)w2mT, 0, 1536, 384, 1536, dflag);

    for (int b0 = 0; b0 < 128; b0 += NB) {
        const size_t xoff = (size_t)b0 * 384 * 768;
        transpose_cvt<<<dim3(24, 12, NB), tb, 0, stream>>>(x, (u16*)Xc, xoff, 384, 768, 384, dflag);

        // per-axis QKV (small L3-resident buffer) + attention into shared ATOc columns
        for (int i = 0; i < 3; ++i) {
            gemm_bt<0><<<dim3(Tc / 128, 9), 256, 0, stream>>>(Xc, qkvT + (size_t)(i * 1152) * 384,
                                                              QKVc, nullptr, nullptr, Tc, 1152, 384);
            if (i == 0)      attn3 <<<NB * 12,  256, 0, stream>>>(QKVc, ATOc,              1152, 1152);
            else if (i == 1) attn16<<<NB * 144, 256, 0, stream>>>(QKVc, ATOc + 384, 16, 1, 1152, 1152);
            else             attn16<<<NB * 144, 256, 0, stream>>>(QKVc, ATOc + 768, 1, 16, 1152, 1152);
        }

        // fused O-projection: sum over 3 axes in one K=1152 GEMM (+ Sum(bo) + residual Xc)
        gemm_bt<1><<<dim3(Tc / 128, 3), 256, 0, stream>>>(ATOc, woTf, ABc, vboS, Xc, Tc, 384, 1152);

        ln_kernel<<<Tc / 4, 256, 0, stream>>>(ABc, T1c, vg1, vbe1, Tc);
        gemm256<2><<<dim3(Tc / 256, 6), 512, 0, stream>>>(T1c, w1mT, BIGc, vb1m, Tc, 1536, 384);
        gemm_bt<1><<<dim3(Tc / 128, 3), 256, 0, stream>>>(BIGc, w2mT, ABc, vb2m, T1c, Tc, 384, 1536);
        ln_kernel<<<Tc / 4, 256, 0, stream>>>(ABc, Xc, vg2, vbe2, Tc);
        transpose_out<<<dim3(12, 24, NB), tb, 0, stream>>>((const u16*)Xc, d_out, xoff, 768, 384, dflag);
    }
}

// Round 20
// 1494.286 us; speedup vs baseline: 1.0213x; 1.0144x over previous
//
#include <hip/hip_runtime.h>

typedef unsigned short u16;
typedef __bf16 bf16;
typedef bf16  bf16x4 __attribute__((ext_vector_type(4)));
typedef bf16  bf16x8 __attribute__((ext_vector_type(8)));
typedef float f32x4  __attribute__((ext_vector_type(4)));

__device__ __forceinline__ u16  f2b(float v) { return __builtin_bit_cast(u16, (bf16)v); }
__device__ __forceinline__ float b2f(u16 b)  { return (float)__builtin_bit_cast(bf16, b); }

// ---------------- dtype probe: flag=1 if float inputs are f32, 0 if bf16 ----------------
__global__ void probe_dtype(const float* xf, int* flag) {
    __shared__ int cnt[256];
    const int tid = threadIdx.x;
    int good = 0;
#pragma unroll
    for (int i = 0; i < 4; ++i) {
        const float a = fabsf(xf[tid * 4 + i]);
        if (a > 9.5e-7f && a < 1.0e6f) good++;   // NaN fails both
    }
    cnt[tid] = good;
    __syncthreads();
    if (tid == 0) { int s = 0; for (int i = 0; i < 256; ++i) s += cnt[i]; *flag = (s > 512) ? 1 : 0; }
}

// ---------------- small-vector convert -> bf16 copy in ws ----------------
__global__ void cvt_vec(const void* in, bf16* out, int n, const int* flag) {
    const int f32 = *flag;
    for (int i = blockIdx.x * 256 + threadIdx.x; i < n; i += gridDim.x * 256)
        out[i] = f32 ? (bf16)(((const float*)in)[i])
                     : __builtin_bit_cast(bf16, ((const u16*)in)[i]);
}

// sum of three vectors (flag dtype) -> bf16
__global__ void sum3_vec(const void* a, const void* b, const void* c, bf16* out, int n, const int* flag) {
    const int f32 = *flag;
    for (int i = blockIdx.x * 256 + threadIdx.x; i < n; i += gridDim.x * 256) {
        float va, vb, vc;
        if (f32) { va = ((const float*)a)[i]; vb = ((const float*)b)[i]; vc = ((const float*)c)[i]; }
        else { va = b2f(((const u16*)a)[i]); vb = b2f(((const u16*)b)[i]); vc = b2f(((const u16*)c)[i]); }
        out[i] = (bf16)(va + vb + vc);
    }
}

// ---- transpose + convert: in[z][R][C] (flag dtype) -> out[z][C][ostride] bf16 ----
__global__ void transpose_cvt(const void* in, u16* out, size_t base_off, int R, int C, int ostride, const int* flag) {
    __shared__ u16 tile[32][34];
    const int f32 = *flag;
    const int c0 = blockIdx.x * 32, r0 = blockIdx.y * 32;
    const size_t bi = base_off + (size_t)blockIdx.z * R * C;
    const size_t bo = (size_t)blockIdx.z * C * ostride;
    const int tx = threadIdx.x, ty = threadIdx.y;
#pragma unroll
    for (int i = 0; i < 4; ++i) {
        const size_t idx = bi + (size_t)(r0 + ty + i * 8) * C + c0 + tx;
        tile[ty + i * 8][tx] = f32 ? f2b(((const float*)in)[idx]) : ((const u16*)in)[idx];
    }
    __syncthreads();
#pragma unroll
    for (int i = 0; i < 4; ++i)
        out[bo + (size_t)(c0 + ty + i * 8) * ostride + r0 + tx] = tile[tx][ty + i * 8];
}

// ---------------- global -> LDS async staging (16B/lane) ----------------
__device__ __forceinline__ void gld_lds16(const bf16* g, bf16* l) {
    __builtin_amdgcn_global_load_lds((__attribute__((address_space(1))) void*)g,
                                     (__attribute__((address_space(3))) void*)l,
                                     16, 0, 0);
}

// ---------------- GEMM 256x256, 8 waves, 2-phase dbuf, swizzled LDS (PROVEN R5-R19) ----------------
// MODE 0: C = acc ; MODE 2: C = gelu(acc + bias[n])
template<int MODE>
__global__ __launch_bounds__(512)
void gemm256(const bf16* __restrict__ A, const bf16* __restrict__ BT,
             bf16* C, const bf16* __restrict__ bias, int M, int N, int K)
{
    __shared__ __align__(16) bf16 sm[65536];        // 128 KB
    const int tid = threadIdx.x;

    const int gx = gridDim.x, gy = gridDim.y;
    int lin = blockIdx.y * gx + blockIdx.x;
    const int nwg = gx * gy;
    const int q = nwg >> 3, r8 = nwg & 7;
    const int xcd = lin & 7, idx = lin >> 3;
    lin = (xcd < r8 ? xcd * (q + 1) : r8 * (q + 1) + (xcd - r8) * q) + idx;
    const int bm0 = (lin / gy) * 256;
    const int bn0 = (lin % gy) * 256;

    const int lane = tid & 63, wid = tid >> 6;
    const int wr = wid >> 2, wc = wid & 3;           // 2x4 waves, wave tile 128x64
    const int fr = lane & 15, fg = lane >> 4;
    const int arow = tid >> 3;                       // 0..63
    const int scol = ((tid & 7) ^ (arow & 7)) << 3;  // pre-swizzled source col

    const bf16* Ab = A  + (size_t)(bm0 + arow) * K + scol;
    const bf16* Bb = BT + (size_t)(bn0 + arow) * K + scol;

    bf16* const lA0 = sm;
    bf16* const lA1 = sm + 16384;
    bf16* const lB0 = sm + 32768;
    bf16* const lB1 = sm + 49152;

    f32x4 acc[8][4] = {};
    const int NT = K >> 6;

#pragma unroll
    for (int i = 0; i < 4; ++i) gld_lds16(Ab + (size_t)i * 64 * K, lA0 + i * 4096 + tid * 8);
#pragma unroll
    for (int i = 0; i < 4; ++i) gld_lds16(Bb + (size_t)i * 64 * K, lB0 + i * 4096 + tid * 8);
    __syncthreads();

    const int sw = fr & 7;
    for (int t = 0; t < NT; ++t) {
        if (t + 1 < NT) {
            const int k0 = (t + 1) << 6;
            bf16* la = ((t + 1) & 1) ? lA1 : lA0;
            bf16* lb = ((t + 1) & 1) ? lB1 : lB0;
#pragma unroll
            for (int i = 0; i < 4; ++i) gld_lds16(Ab + k0 + (size_t)i * 64 * K, la + i * 4096 + tid * 8);
#pragma unroll
            for (int i = 0; i < 4; ++i) gld_lds16(Bb + k0 + (size_t)i * 64 * K, lb + i * 4096 + tid * 8);
        }
        const bf16* la = (t & 1) ? lA1 : lA0;
        const bf16* lb = (t & 1) ? lB1 : lB0;
#pragma unroll
        for (int kk = 0; kk < 2; ++kk) {
            const int so = ((((kk << 2) + fg) ^ sw) << 3);
            bf16x8 bfv[4];
#pragma unroll
            for (int n = 0; n < 4; ++n)
                bfv[n] = *(const bf16x8*)&lb[(wc * 64 + n * 16 + fr) * 64 + so];
#pragma unroll
            for (int m = 0; m < 8; ++m) {
                const bf16x8 af = *(const bf16x8*)&la[(wr * 128 + m * 16 + fr) * 64 + so];
#pragma unroll
                for (int n = 0; n < 4; ++n)
                    acc[m][n] = __builtin_amdgcn_mfma_f32_16x16x32_bf16(af, bfv[n], acc[m][n], 0, 0, 0);
            }
        }
        __syncthreads();
    }

    // epilogue: acc (+bias/gelu) -> LDS bf16 [256][256] -> coalesced 16B stores
#pragma unroll
    for (int n = 0; n < 4; ++n) {
        const int col = wc * 64 + n * 16 + fr;
        const float bv = (MODE == 2) ? (float)bias[bn0 + col] : 0.f;
#pragma unroll
        for (int m = 0; m < 8; ++m) {
            const int row0 = wr * 128 + m * 16 + fg * 4;
#pragma unroll
            for (int r = 0; r < 4; ++r) {
                float v = acc[m][n][r];
                if (MODE == 2) { v += bv; v = 0.5f * v * (1.f + erff(v * 0.70710678118654752f)); }
                sm[(row0 + r) * 256 + col] = (bf16)v;
            }
        }
    }
    __syncthreads();
#pragma unroll
    for (int it = 0; it < 16; ++it) {
        const int chunk = it * 512 + tid;
        const int row = chunk >> 5, c8 = (chunk & 31) << 3;
        *(bf16x8*)&C[(size_t)(bm0 + row) * N + bn0 + c8] = *(const bf16x8*)&sm[row * 256 + c8];
    }
}

// ======== GEMM 128x128: SINGLE-buffer m97 2-barrier loop, 32KB LDS (PROVEN R13-R19) ========
// MODE 0: C = acc ; MODE 1: C = acc + bias[n] + add[m,n]
template<int MODE>
__global__ __launch_bounds__(256)
void gemm_bt(const bf16* __restrict__ A, const bf16* __restrict__ BT,
             bf16* C, const bf16* __restrict__ bias,
             const bf16* add, int M, int N, int K)
{
    __shared__ __align__(16) bf16 sm[16384];         // 32 KB: stage A(16KB)+B(16KB); epi: f32 64x128
    const int tid = threadIdx.x;

    const int gx = gridDim.x, gy = gridDim.y;
    int lin = blockIdx.y * gx + blockIdx.x;
    const int nwg = gx * gy;
    const int q = nwg >> 3, r8 = nwg & 7;
    const int xcd = lin & 7, idx = lin >> 3;
    lin = (xcd < r8 ? xcd * (q + 1) : r8 * (q + 1) + (xcd - r8) * q) + idx;
    const int bm0 = (lin / gy) * 128;
    const int bn0 = (lin % gy) * 128;

    const int lane = tid & 63, wid = tid >> 6;
    const int wr = wid >> 1, wc = wid & 1;           // 2x2 waves, wave tile 64x64
    const int fr = lane & 15, fg = lane >> 4;
    const int arow = tid >> 3;                       // 0..31
    const int scol = ((tid & 7) ^ (arow & 7)) << 3;

    const bf16* Ab = A  + (size_t)(bm0 + arow) * K + scol;
    const bf16* Bb = BT + (size_t)(bn0 + arow) * K + scol;

    bf16* const lA = sm;                             // 128x64
    bf16* const lB = sm + 8192;

    f32x4 acc[4][4] = {};
    const int NT = K >> 6;
    const int sw = fr & 7;

    for (int t = 0; t < NT; ++t) {
        __syncthreads();                             // WAR: previous compute reads retired
        const int k0 = t << 6;
#pragma unroll
        for (int i = 0; i < 4; ++i) gld_lds16(Ab + k0 + (size_t)i * 32 * K, lA + i * 2048 + tid * 8);
#pragma unroll
        for (int i = 0; i < 4; ++i) gld_lds16(Bb + k0 + (size_t)i * 32 * K, lB + i * 2048 + tid * 8);
        __syncthreads();                             // RAW: vmcnt drained, stage visible
#pragma unroll
        for (int kk = 0; kk < 2; ++kk) {
            bf16x8 af[4], bfv[4];
#pragma unroll
            for (int m = 0; m < 4; ++m)
                af[m] = *(const bf16x8*)&lA[(wr * 64 + m * 16 + fr) * 64 + ((((kk << 2) + fg) ^ sw) << 3)];
#pragma unroll
            for (int n = 0; n < 4; ++n)
                bfv[n] = *(const bf16x8*)&lB[(wc * 64 + n * 16 + fr) * 64 + ((((kk << 2) + fg) ^ sw) << 3)];
#pragma unroll
            for (int m = 0; m < 4; ++m)
#pragma unroll
                for (int n = 0; n < 4; ++n)
                    acc[m][n] = __builtin_amdgcn_mfma_f32_16x16x32_bf16(af[m], bfv[n], acc[m][n], 0, 0, 0);
        }
    }
    __syncthreads();                                 // all compute reads done before epi reuse

    // ---- epilogue: two 64-row halves via f32 [64][128] tile, barriered ----
    float* lc = (float*)sm;
#pragma unroll
    for (int half = 0; half < 2; ++half) {
        if (wr == half) {                            // wave-uniform branch
#pragma unroll
            for (int n = 0; n < 4; ++n) {
                const int col = wc * 64 + n * 16 + fr;
#pragma unroll
                for (int m = 0; m < 4; ++m)
#pragma unroll
                    for (int r2 = 0; r2 < 4; ++r2)
                        lc[(m * 16 + fg * 4 + r2) * 128 + col] = acc[m][n][r2];
            }
        }
        __syncthreads();                             // stores visible to all waves
#pragma unroll
        for (int i = 0; i < 8; ++i) {
            const int chunk = i * 256 + tid;         // 2048 chunks = 64x128 / 4
            const int row = chunk >> 5, cb = (chunk & 31) * 4;
            const size_t goff = (size_t)(bm0 + half * 64 + row) * N + bn0 + cb;
            const f32x4 v = ((const f32x4*)lc)[chunk];
            bf16x4 o;
            if (MODE == 1) {
                const bf16x4 bv = *(const bf16x4*)&bias[bn0 + cb];
                const bf16x4 av = *(const bf16x4*)&add[goff];
#pragma unroll
                for (int e = 0; e < 4; ++e) o[e] = (bf16)(v[e] + (float)bv[e] + (float)av[e]);
            } else {
#pragma unroll
                for (int e = 0; e < 4; ++e) o[e] = (bf16)v[e];
            }
            *(bf16x4*)&C[goff] = o;
        }
        __syncthreads();                             // reads done before next half overwrites
    }
}

// ---- attention, T=16: one wave per (seq, head); qs = QKV row stride, os = output row stride ----
__global__ __launch_bounds__(256)
void attn16(const bf16* __restrict__ QKV, bf16* __restrict__ O, int tstride, int lastmul, int qs, int os)
{
    const int lane = threadIdx.x & 63;
    const int gw   = (blockIdx.x * 256 + threadIdx.x) >> 6;
    const int head = gw % 12;
    const int seq  = gw / 12;
    const int b    = seq / 48, r2 = seq % 48;
    const int s    = r2 >> 4, last = r2 & 15;
    const int tbase = b * 768 + s * 256 + last * lastmul;
    const int fr = lane & 15, fg = lane >> 4;

    const size_t rowQ = (size_t)(tbase + fr * tstride) * qs + head * 32 + fg * 8;
    const bf16x8 kf = *(const bf16x8*)(QKV + rowQ + 384);
    const bf16x8 qf = *(const bf16x8*)(QKV + rowQ);
    const f32x4 z = {0.f, 0.f, 0.f, 0.f};
    f32x4 S = __builtin_amdgcn_mfma_f32_16x16x32_bf16(kf, qf, z, 0, 0, 0);

    const float sc = 0.17677669529663687f;
    float mx = fmaxf(fmaxf(S[0], S[1]), fmaxf(S[2], S[3]));
    mx = fmaxf(mx, __shfl_xor(mx, 16));
    mx = fmaxf(mx, __shfl_xor(mx, 32));
    float p[4], sum = 0.f;
#pragma unroll
    for (int r = 0; r < 4; ++r) { p[r] = __expf((S[r] - mx) * sc); sum += p[r]; }
    sum += __shfl_xor(sum, 16);
    sum += __shfl_xor(sum, 32);
    const float inv = 1.f / sum;

    bf16x8 pa;
#pragma unroll
    for (int j = 0; j < 8; ++j) {
        const int srcg = 2 * fg + (j >> 2);
        const float v = __shfl(p[j & 3], fr + 16 * (srcg & 3));
        pa[j] = (bf16)(fg < 2 ? v * inv : 0.f);
    }

#pragma unroll
    for (int t = 0; t < 2; ++t) {
        bf16x8 vf;
#pragma unroll
        for (int j = 0; j < 8; ++j) {
            const int key = fg * 8 + j;
            vf[j] = (fg < 2)
                ? QKV[(size_t)(tbase + key * tstride) * qs + 768 + head * 32 + fr + 16 * t]
                : (bf16)0.f;
        }
        f32x4 o = __builtin_amdgcn_mfma_f32_16x16x32_bf16(pa, vf, z, 0, 0, 0);
#pragma unroll
        for (int r = 0; r < 4; ++r)
            O[(size_t)(tbase + (fg * 4 + r) * tstride) * os + head * 32 + fr + 16 * t] = (bf16)o[r];
    }
}

// ---------------- attention, T=3: one thread per (seq, head) ----------------
__global__ __launch_bounds__(256)
void attn3(const bf16* __restrict__ QKV, bf16* __restrict__ O, int qs, int os)
{
    const int t    = blockIdx.x * 256 + threadIdx.x;
    const int head = t % 12;
    const int seq  = t / 12;
    const int b    = seq >> 8, hw = seq & 255;
    const size_t base  = (size_t)(b * 768 + hw) * qs + head * 32;
    const size_t tstep = (size_t)256 * qs;

    float s[3][3] = {};
#pragma unroll
    for (int c = 0; c < 4; ++c) {
        bf16x8 q[3], k[3];
#pragma unroll
        for (int i = 0; i < 3; ++i) {
            q[i] = *(const bf16x8*)(QKV + base + i * tstep + c * 8);
            k[i] = *(const bf16x8*)(QKV + base + i * tstep + 384 + c * 8);
        }
#pragma unroll
        for (int i = 0; i < 3; ++i)
#pragma unroll
            for (int j = 0; j < 3; ++j) {
                float a = 0.f;
#pragma unroll
                for (int e = 0; e < 8; ++e) a += (float)q[i][e] * (float)k[j][e];
                s[i][j] += a;
            }
    }
    const float sc = 0.17677669529663687f;
    float p[3][3];
#pragma unroll
    for (int i = 0; i < 3; ++i) {
        const float mx = fmaxf(s[i][0], fmaxf(s[i][1], s[i][2]));
        float sum = 0.f;
#pragma unroll
        for (int j = 0; j < 3; ++j) { p[i][j] = __expf((s[i][j] - mx) * sc); sum += p[i][j]; }
        const float inv = 1.f / sum;
#pragma unroll
        for (int j = 0; j < 3; ++j) p[i][j] *= inv;
    }
    const size_t obase = (size_t)(b * 768 + hw) * os + head * 32;
#pragma unroll
    for (int c = 0; c < 4; ++c) {
        bf16x8 v[3];
#pragma unroll
        for (int j = 0; j < 3; ++j) v[j] = *(const bf16x8*)(QKV + base + j * tstep + 768 + c * 8);
#pragma unroll
        for (int i = 0; i < 3; ++i) {
            bf16x8 ov;
#pragma unroll
            for (int e = 0; e < 8; ++e)
                ov[e] = (bf16)(p[i][0] * (float)v[0][e] + p[i][1] * (float)v[1][e] + p[i][2] * (float)v[2][e]);
            *(bf16x8*)(O + obase + (size_t)i * 256 * os + c * 8) = ov;
        }
    }
}

// ---------------- LayerNorm over 384, one wave per token (LN1, unchanged) ----------------
__global__ __launch_bounds__(256)
void ln_kernel(const bf16* __restrict__ in, bf16* __restrict__ out,
               const bf16* __restrict__ g, const bf16* __restrict__ be, int ntok)
{
    const int w    = (blockIdx.x * 256 + threadIdx.x) >> 6;
    const int lane = threadIdx.x & 63;
    if (w >= ntok) return;
    const bf16* row = in + (size_t)w * 384;
    float x[6], sum = 0.f;
#pragma unroll
    for (int i = 0; i < 6; ++i) { x[i] = (float)row[lane + i * 64]; sum += x[i]; }
#pragma unroll
    for (int o = 32; o >= 1; o >>= 1) sum += __shfl_xor(sum, o);
    const float mu = sum * (1.f / 384.f);
    float vs = 0.f;
#pragma unroll
    for (int i = 0; i < 6; ++i) { const float d = x[i] - mu; vs += d * d; }
#pragma unroll
    for (int o = 32; o >= 1; o >>= 1) vs += __shfl_xor(vs, o);
    const float rstd = rsqrtf(vs * (1.f / 384.f) + 1e-5f);
    bf16* orow = out + (size_t)w * 384;
#pragma unroll
    for (int i = 0; i < 6; ++i)
        orow[lane + i * 64] = (bf16)((x[i] - mu) * rstd * (float)g[lane + i * 64] + (float)be[lane + i * 64]);
}

// ======== fused LN2 + output transpose: in[Tc][384] -> LN -> out[z][384][768] (flag dtype) ========
// grid (24, NB); block = 256 thr = 4 waves; each block = 32 consecutive tokens of batch z.
__global__ __launch_bounds__(256)
void ln_transpose_out(const bf16* __restrict__ in, void* out, size_t base_off,
                      const bf16* __restrict__ g, const bf16* __restrict__ be, const int* flag)
{
    __shared__ bf16 tile[32][388];                  // pad 388 -> 2-way bank conflict (free)
    const int f32 = *flag;
    const int tid = threadIdx.x;
    const int lane = tid & 63, w = tid >> 6;        // wave 0..3
    const int r0 = blockIdx.x * 32;                 // token window within batch image
    const int zz = blockIdx.y;
    const bf16* inz = in + ((size_t)zz * 768 + r0) * 384;

#pragma unroll
    for (int p = 0; p < 8; ++p) {                   // 8 passes x 4 waves = 32 tokens
        const int tok = p * 4 + w;
        const bf16* row = inz + (size_t)tok * 384;
        float x[6], sum = 0.f;
#pragma unroll
        for (int i = 0; i < 6; ++i) { x[i] = (float)row[lane + i * 64]; sum += x[i]; }
#pragma unroll
        for (int o = 32; o >= 1; o >>= 1) sum += __shfl_xor(sum, o);
        const float mu = sum * (1.f / 384.f);
        float vs = 0.f;
#pragma unroll
        for (int i = 0; i < 6; ++i) { const float d = x[i] - mu; vs += d * d; }
#pragma unroll
        for (int o = 32; o >= 1; o >>= 1) vs += __shfl_xor(vs, o);
        const float rstd = rsqrtf(vs * (1.f / 384.f) + 1e-5f);
#pragma unroll
        for (int i = 0; i < 6; ++i)
            tile[tok][lane + i * 64] =
                (bf16)((x[i] - mu) * rstd * (float)g[lane + i * 64] + (float)be[lane + i * 64]);
    }
    __syncthreads();

    // transposed write: out[z][c][768], cols r0..r0+31; 32 consecutive r per thread-row
    const size_t bo = base_off + (size_t)zz * 384 * 768;
#pragma unroll
    for (int it = 0; it < 48; ++it) {               // 384*32 / 256
        const int idx = it * 256 + tid;
        const int c = idx >> 5, r = idx & 31;
        const u16 v = __builtin_bit_cast(u16, tile[r][c]);
        const size_t o = bo + (size_t)c * 768 + r0 + r;
        if (f32) ((float*)out)[o] = b2f(v); else ((u16*)out)[o] = v;
    }
}

// ---------------- launch ----------------
extern "C" void kernel_launch(void* const* d_in, const int* in_sizes, int n_in,
                              void* d_out, int out_size, void* d_ws, size_t ws_size,
                              hipStream_t stream)
{
    const void* x = d_in[0];
    const void *Wq[3], *Wkv[3], *Wo[3], *bo[3];
    for (int i = 0; i < 3; ++i) {
        Wq[i]  = d_in[1 + 4 * i];
        Wkv[i] = d_in[2 + 4 * i];
        Wo[i]  = d_in[3 + 4 * i];
        bo[i]  = d_in[4 + 4 * i];
    }
    const void* g1  = d_in[13];
    const void* be1 = d_in[14];
    const void* W1m = d_in[15];
    const void* b1m = d_in[16];
    const void* W2m = d_in[17];
    const void* b2m = d_in[18];
    const void* g2  = d_in[19];
    const void* be2 = d_in[20];

    // ---- workspace layout ----
    char* ws = (char*)d_ws;
    bf16* qkvT = (bf16*)(ws);                       // [3456][384] per-axis QKV weights (i*1152 rows)
    bf16* woTf = (bf16*)(ws + 2654208ull);          // [384][1152] stacked O-proj weights
    bf16* w1mT = (bf16*)(ws + 3538944ull);          // [1536][384]
    bf16* w2mT = (bf16*)(ws + 4718592ull);          // [384][1536]
    bf16 *vboS, *vg1, *vbe1, *vg2, *vbe2, *vb1m, *vb2m;
    {
        char* vp = ws + 5898240ull;
        vboS = (bf16*)(vp);
        vg1  = (bf16*)(vp + 768);        vbe1 = (bf16*)(vp + 1536);
        vg2  = (bf16*)(vp + 2304);       vbe2 = (bf16*)(vp + 3072);
        vb1m = (bf16*)(vp + 3840);       vb2m = (bf16*)(vp + 6912);
    }
    int* dflag = (int*)(ws + 5909504ull);
    const size_t WB = 6553600ull;                   // chunk region base

    // chunk size: NB=32 (4 chunks); live set during QKV/attn ~132MB -> L3-resident
    int NB = 32;
    while (NB > 2) {
        size_t need = WB + (size_t)NB * 768 * (3 * 384 + 2 * 1152 + 1536) * 2;
        if (need <= ws_size) break;
        NB >>= 1;
    }
    const int Tc = NB * 768;
    const size_t tokB = (size_t)Tc * 384 * 2;
    bf16* Xc    = (bf16*)(ws + WB);
    bf16* ABc   = (bf16*)(ws + WB + tokB);
    bf16* T1c   = (bf16*)(ws + WB + 2 * tokB);
    bf16* ATOc  = (bf16*)(ws + WB + 3 * tokB);      // Tc x 1152 (3 axes side by side)
    bf16* QKVc  = (bf16*)(ws + WB + 6 * tokB);      // Tc x 1152 (one axis at a time)
    bf16* BIGc  = (bf16*)(ws + WB + 9 * tokB);      // Tc x 1536 (MLP hidden)

    // ---- dtype probe + conversions ----
    probe_dtype<<<1, 256, 0, stream>>>((const float*)x, dflag);
    sum3_vec<<<2, 256, 0, stream>>>(bo[0], bo[1], bo[2], vboS, 384, dflag);
    cvt_vec<<<2, 256, 0, stream>>>(g1,  vg1,  384,  dflag);
    cvt_vec<<<2, 256, 0, stream>>>(be1, vbe1, 384,  dflag);
    cvt_vec<<<2, 256, 0, stream>>>(g2,  vg2,  384,  dflag);
    cvt_vec<<<2, 256, 0, stream>>>(be2, vbe2, 384,  dflag);
    cvt_vec<<<6, 256, 0, stream>>>(b1m, vb1m, 1536, dflag);
    cvt_vec<<<2, 256, 0, stream>>>(b2m, vb2m, 384,  dflag);

    const dim3 tb(32, 8);
    for (int i = 0; i < 3; ++i) {
        transpose_cvt<<<dim3(12, 12, 1), tb, 0, stream>>>(Wq[i],  (u16*)(qkvT + (size_t)(i * 1152) * 384),       0, 384, 384, 384, dflag);
        transpose_cvt<<<dim3(24, 12, 1), tb, 0, stream>>>(Wkv[i], (u16*)(qkvT + (size_t)(i * 1152 + 384) * 384), 0, 384, 768, 384, dflag);
        transpose_cvt<<<dim3(12, 12, 1), tb, 0, stream>>>(Wo[i],  (u16*)(woTf + i * 384),                        0, 384, 384, 1152, dflag);
    }
    transpose_cvt<<<dim3(48, 12, 1), tb, 0, stream>>>(W1m, (u16*)w1mT, 0, 384, 1536, 384,  dflag);
    transpose_cvt<<<dim3(12, 48, 1), tb, 0, stream>>>(W2m, (u16*)w2mT, 0, 1536, 384, 1536, dflag);

    for (int b0 = 0; b0 < 128; b0 += NB) {
        const size_t xoff = (size_t)b0 * 384 * 768;
        transpose_cvt<<<dim3(24, 12, NB), tb, 0, stream>>>(x, (u16*)Xc, xoff, 384, 768, 384, dflag);

        // per-axis QKV (small L3-resident buffer) + attention into shared ATOc columns
        for (int i = 0; i < 3; ++i) {
            gemm_bt<0><<<dim3(Tc / 128, 9), 256, 0, stream>>>(Xc, qkvT + (size_t)(i * 1152) * 384,
                                                              QKVc, nullptr, nullptr, Tc, 1152, 384);
            if (i == 0)      attn3 <<<NB * 12,  256, 0, stream>>>(QKVc, ATOc,              1152, 1152);
            else if (i == 1) attn16<<<NB * 144, 256, 0, stream>>>(QKVc, ATOc + 384, 16, 1, 1152, 1152);
            else             attn16<<<NB * 144, 256, 0, stream>>>(QKVc, ATOc + 768, 1, 16, 1152, 1152);
        }

        // fused O-projection: sum over 3 axes in one K=1152 GEMM (+ Sum(bo) + residual Xc)
        gemm_bt<1><<<dim3(Tc / 128, 3), 256, 0, stream>>>(ATOc, woTf, ABc, vboS, Xc, Tc, 384, 1152);

        ln_kernel<<<Tc / 4, 256, 0, stream>>>(ABc, T1c, vg1, vbe1, Tc);
        gemm256<2><<<dim3(Tc / 256, 6), 512, 0, stream>>>(T1c, w1mT, BIGc, vb1m, Tc, 1536, 384);
        gemm_bt<1><<<dim3(Tc / 128, 3), 256, 0, stream>>>(BIGc, w2mT, ABc, vb2m, T1c, Tc, 384, 1536);
        // fused LN2 + transpose straight to d_out (saves the Xc round-trip)
        ln_transpose_out<<<dim3(24, NB), 256, 0, stream>>>(ABc, d_out, xoff, vg2, vbe2, dflag);
    }
}

// Round 21
// 1448.344 us; speedup vs baseline: 1.0537x; 1.0317x over previous
//
#include <hip/hip_runtime.h>

typedef unsigned short u16;
typedef __bf16 bf16;
typedef bf16  bf16x4 __attribute__((ext_vector_type(4)));
typedef bf16  bf16x8 __attribute__((ext_vector_type(8)));
typedef float f32x4  __attribute__((ext_vector_type(4)));

__device__ __forceinline__ u16  f2b(float v) { return __builtin_bit_cast(u16, (bf16)v); }
__device__ __forceinline__ float b2f(u16 b)  { return (float)__builtin_bit_cast(bf16, b); }

// ---------------- dtype probe: flag=1 if float inputs are f32, 0 if bf16 ----------------
__global__ void probe_dtype(const float* xf, int* flag) {
    __shared__ int cnt[256];
    const int tid = threadIdx.x;
    int good = 0;
#pragma unroll
    for (int i = 0; i < 4; ++i) {
        const float a = fabsf(xf[tid * 4 + i]);
        if (a > 9.5e-7f && a < 1.0e6f) good++;   // NaN fails both
    }
    cnt[tid] = good;
    __syncthreads();
    if (tid == 0) { int s = 0; for (int i = 0; i < 256; ++i) s += cnt[i]; *flag = (s > 512) ? 1 : 0; }
}

__device__ __forceinline__ float rd_flag(const void* p, int i, int f32) {
    return f32 ? ((const float*)p)[i] : b2f(((const u16*)p)[i]);
}

// ======== consolidated small-vector conversion: all 7 vectors (3840 elems) in ONE kernel ========
// vp layout (bf16 elems): vboS@0(384)=bo0+bo1+bo2, vg1@384, vbe1@768, vg2@1152, vbe2@1536,
//                         vb1m@1920(1536), vb2m@3456(384)
__global__ __launch_bounds__(256)
void cvt_all(const void* bo0, const void* bo1, const void* bo2,
             const void* g1, const void* be1, const void* g2, const void* be2,
             const void* b1m, const void* b2m, bf16* vp, const int* flag)
{
    const int f32 = *flag;
    const int i = blockIdx.x * 256 + threadIdx.x;   // 15 blocks x 256 = 3840
    if (i < 384) {
        vp[i] = (bf16)(rd_flag(bo0, i, f32) + rd_flag(bo1, i, f32) + rd_flag(bo2, i, f32));
    } else if (i < 768)  { vp[i] = (bf16)rd_flag(g1,  i - 384,  f32); }
    else if (i < 1152)   { vp[i] = (bf16)rd_flag(be1, i - 768,  f32); }
    else if (i < 1536)   { vp[i] = (bf16)rd_flag(g2,  i - 1152, f32); }
    else if (i < 1920)   { vp[i] = (bf16)rd_flag(be2, i - 1536, f32); }
    else if (i < 3456)   { vp[i] = (bf16)rd_flag(b1m, i - 1920, f32); }
    else                 { vp[i] = (bf16)rd_flag(b2m, i - 3456, f32); }
}

// ======== consolidated weight transposes: all 11 matrices (2880 tiles) in ONE kernel ========
struct SrcPtrs { const void* p[11]; };
__global__ __launch_bounds__(256)
void wtrans_all(SrcPtrs srcs, u16* wsbase, const int* flag)
{
    // segment tables (tile counts = (C/32)*(R/32))
    const int prefix[12] = {0, 144, 432, 576, 720, 1008, 1152, 1296, 1584, 1728, 2304, 2880};
    const int Carr[11]   = {384, 768, 384,  384, 768, 384,  384, 768, 384,  1536, 384};
    const int Rarr[11]   = {384, 384, 384,  384, 384, 384,  384, 384, 384,  384, 1536};
    const int OSarr[11]  = {384, 384, 1152, 384, 384, 1152, 384, 384, 1152, 384, 1536};
    const int DOarr[11]  = {0, 147456, 1327104, 442368, 589824, 1327488,
                            884736, 1032192, 1327872, 1769472, 2359296};

    __shared__ u16 tile[32][34];
    const int f32 = *flag;
    const int bid = blockIdx.x;
    int s = 0;
#pragma unroll
    for (int k = 0; k < 11; ++k) if (bid >= prefix[k + 1]) s = k + 1;
    const int tix = bid - prefix[s];
    const int C = Carr[s], R = Rarr[s], ostride = OSarr[s];
    const int tilesX = C >> 5;
    const int c0 = (tix % tilesX) * 32, r0 = (tix / tilesX) * 32;
    const void* in = srcs.p[s];
    u16* out = wsbase + DOarr[s];

    const int tx = threadIdx.x & 31, ty = threadIdx.x >> 5;   // 32 x 8
#pragma unroll
    for (int i = 0; i < 4; ++i) {
        const int idx = (r0 + ty + i * 8) * C + c0 + tx;
        tile[ty + i * 8][tx] = f32 ? f2b(((const float*)in)[idx]) : ((const u16*)in)[idx];
    }
    __syncthreads();
#pragma unroll
    for (int i = 0; i < 4; ++i)
        out[(size_t)(c0 + ty + i * 8) * ostride + r0 + tx] = tile[tx][ty + i * 8];
}

// ---- transpose + convert: in[z][R][C] (flag dtype) -> out[z][C][ostride] bf16 (input x) ----
__global__ void transpose_cvt(const void* in, u16* out, size_t base_off, int R, int C, int ostride, const int* flag) {
    __shared__ u16 tile[32][34];
    const int f32 = *flag;
    const int c0 = blockIdx.x * 32, r0 = blockIdx.y * 32;
    const size_t bi = base_off + (size_t)blockIdx.z * R * C;
    const size_t bo = (size_t)blockIdx.z * C * ostride;
    const int tx = threadIdx.x, ty = threadIdx.y;
#pragma unroll
    for (int i = 0; i < 4; ++i) {
        const size_t idx = bi + (size_t)(r0 + ty + i * 8) * C + c0 + tx;
        tile[ty + i * 8][tx] = f32 ? f2b(((const float*)in)[idx]) : ((const u16*)in)[idx];
    }
    __syncthreads();
#pragma unroll
    for (int i = 0; i < 4; ++i)
        out[bo + (size_t)(c0 + ty + i * 8) * ostride + r0 + tx] = tile[tx][ty + i * 8];
}

// ---------------- global -> LDS async staging (16B/lane) ----------------
__device__ __forceinline__ void gld_lds16(const bf16* g, bf16* l) {
    __builtin_amdgcn_global_load_lds((__attribute__((address_space(1))) void*)g,
                                     (__attribute__((address_space(3))) void*)l,
                                     16, 0, 0);
}

// ---------------- GEMM 256x256, 8 waves, 2-phase dbuf, swizzled LDS (PROVEN R5-R20) ----------------
// MODE 0: C = acc ; MODE 2: C = gelu(acc + bias[n])
template<int MODE>
__global__ __launch_bounds__(512)
void gemm256(const bf16* __restrict__ A, const bf16* __restrict__ BT,
             bf16* C, const bf16* __restrict__ bias, int M, int N, int K)
{
    __shared__ __align__(16) bf16 sm[65536];        // 128 KB
    const int tid = threadIdx.x;

    const int gx = gridDim.x, gy = gridDim.y;
    int lin = blockIdx.y * gx + blockIdx.x;
    const int nwg = gx * gy;
    const int q = nwg >> 3, r8 = nwg & 7;
    const int xcd = lin & 7, idx = lin >> 3;
    lin = (xcd < r8 ? xcd * (q + 1) : r8 * (q + 1) + (xcd - r8) * q) + idx;
    const int bm0 = (lin / gy) * 256;
    const int bn0 = (lin % gy) * 256;

    const int lane = tid & 63, wid = tid >> 6;
    const int wr = wid >> 2, wc = wid & 3;           // 2x4 waves, wave tile 128x64
    const int fr = lane & 15, fg = lane >> 4;
    const int arow = tid >> 3;                       // 0..63
    const int scol = ((tid & 7) ^ (arow & 7)) << 3;  // pre-swizzled source col

    const bf16* Ab = A  + (size_t)(bm0 + arow) * K + scol;
    const bf16* Bb = BT + (size_t)(bn0 + arow) * K + scol;

    bf16* const lA0 = sm;
    bf16* const lA1 = sm + 16384;
    bf16* const lB0 = sm + 32768;
    bf16* const lB1 = sm + 49152;

    f32x4 acc[8][4] = {};
    const int NT = K >> 6;

#pragma unroll
    for (int i = 0; i < 4; ++i) gld_lds16(Ab + (size_t)i * 64 * K, lA0 + i * 4096 + tid * 8);
#pragma unroll
    for (int i = 0; i < 4; ++i) gld_lds16(Bb + (size_t)i * 64 * K, lB0 + i * 4096 + tid * 8);
    __syncthreads();

    const int sw = fr & 7;
    for (int t = 0; t < NT; ++t) {
        if (t + 1 < NT) {
            const int k0 = (t + 1) << 6;
            bf16* la = ((t + 1) & 1) ? lA1 : lA0;
            bf16* lb = ((t + 1) & 1) ? lB1 : lB0;
#pragma unroll
            for (int i = 0; i < 4; ++i) gld_lds16(Ab + k0 + (size_t)i * 64 * K, la + i * 4096 + tid * 8);
#pragma unroll
            for (int i = 0; i < 4; ++i) gld_lds16(Bb + k0 + (size_t)i * 64 * K, lb + i * 4096 + tid * 8);
        }
        const bf16* la = (t & 1) ? lA1 : lA0;
        const bf16* lb = (t & 1) ? lB1 : lB0;
#pragma unroll
        for (int kk = 0; kk < 2; ++kk) {
            const int so = ((((kk << 2) + fg) ^ sw) << 3);
            bf16x8 bfv[4];
#pragma unroll
            for (int n = 0; n < 4; ++n)
                bfv[n] = *(const bf16x8*)&lb[(wc * 64 + n * 16 + fr) * 64 + so];
#pragma unroll
            for (int m = 0; m < 8; ++m) {
                const bf16x8 af = *(const bf16x8*)&la[(wr * 128 + m * 16 + fr) * 64 + so];
#pragma unroll
                for (int n = 0; n < 4; ++n)
                    acc[m][n] = __builtin_amdgcn_mfma_f32_16x16x32_bf16(af, bfv[n], acc[m][n], 0, 0, 0);
            }
        }
        __syncthreads();
    }

    // epilogue: acc (+bias/gelu) -> LDS bf16 [256][256] -> coalesced 16B stores
#pragma unroll
    for (int n = 0; n < 4; ++n) {
        const int col = wc * 64 + n * 16 + fr;
        const float bv = (MODE == 2) ? (float)bias[bn0 + col] : 0.f;
#pragma unroll
        for (int m = 0; m < 8; ++m) {
            const int row0 = wr * 128 + m * 16 + fg * 4;
#pragma unroll
            for (int r = 0; r < 4; ++r) {
                float v = acc[m][n][r];
                if (MODE == 2) { v += bv; v = 0.5f * v * (1.f + erff(v * 0.70710678118654752f)); }
                sm[(row0 + r) * 256 + col] = (bf16)v;
            }
        }
    }
    __syncthreads();
#pragma unroll
    for (int it = 0; it < 16; ++it) {
        const int chunk = it * 512 + tid;
        const int row = chunk >> 5, c8 = (chunk & 31) << 3;
        *(bf16x8*)&C[(size_t)(bm0 + row) * N + bn0 + c8] = *(const bf16x8*)&sm[row * 256 + c8];
    }
}

// ======== GEMM 128x128: SINGLE-buffer m97 2-barrier loop, 32KB LDS (PROVEN R13-R20) ========
// MODE 0: C = acc ; MODE 1: C = acc + bias[n] + add[m,n]
template<int MODE>
__global__ __launch_bounds__(256)
void gemm_bt(const bf16* __restrict__ A, const bf16* __restrict__ BT,
             bf16* C, const bf16* __restrict__ bias,
             const bf16* add, int M, int N, int K)
{
    __shared__ __align__(16) bf16 sm[16384];         // 32 KB: stage A(16KB)+B(16KB); epi: f32 64x128
    const int tid = threadIdx.x;

    const int gx = gridDim.x, gy = gridDim.y;
    int lin = blockIdx.y * gx + blockIdx.x;
    const int nwg = gx * gy;
    const int q = nwg >> 3, r8 = nwg & 7;
    const int xcd = lin & 7, idx = lin >> 3;
    lin = (xcd < r8 ? xcd * (q + 1) : r8 * (q + 1) + (xcd - r8) * q) + idx;
    const int bm0 = (lin / gy) * 128;
    const int bn0 = (lin % gy) * 128;

    const int lane = tid & 63, wid = tid >> 6;
    const int wr = wid >> 1, wc = wid & 1;           // 2x2 waves, wave tile 64x64
    const int fr = lane & 15, fg = lane >> 4;
    const int arow = tid >> 3;                       // 0..31
    const int scol = ((tid & 7) ^ (arow & 7)) << 3;

    const bf16* Ab = A  + (size_t)(bm0 + arow) * K + scol;
    const bf16* Bb = BT + (size_t)(bn0 + arow) * K + scol;

    bf16* const lA = sm;                             // 128x64
    bf16* const lB = sm + 8192;

    f32x4 acc[4][4] = {};
    const int NT = K >> 6;
    const int sw = fr & 7;

    for (int t = 0; t < NT; ++t) {
        __syncthreads();                             // WAR: previous compute reads retired
        const int k0 = t << 6;
#pragma unroll
        for (int i = 0; i < 4; ++i) gld_lds16(Ab + k0 + (size_t)i * 32 * K, lA + i * 2048 + tid * 8);
#pragma unroll
        for (int i = 0; i < 4; ++i) gld_lds16(Bb + k0 + (size_t)i * 32 * K, lB + i * 2048 + tid * 8);
        __syncthreads();                             // RAW: vmcnt drained, stage visible
#pragma unroll
        for (int kk = 0; kk < 2; ++kk) {
            bf16x8 af[4], bfv[4];
#pragma unroll
            for (int m = 0; m < 4; ++m)
                af[m] = *(const bf16x8*)&lA[(wr * 64 + m * 16 + fr) * 64 + ((((kk << 2) + fg) ^ sw) << 3)];
#pragma unroll
            for (int n = 0; n < 4; ++n)
                bfv[n] = *(const bf16x8*)&lB[(wc * 64 + n * 16 + fr) * 64 + ((((kk << 2) + fg) ^ sw) << 3)];
#pragma unroll
            for (int m = 0; m < 4; ++m)
#pragma unroll
                for (int n = 0; n < 4; ++n)
                    acc[m][n] = __builtin_amdgcn_mfma_f32_16x16x32_bf16(af[m], bfv[n], acc[m][n], 0, 0, 0);
        }
    }
    __syncthreads();                                 // all compute reads done before epi reuse

    // ---- epilogue: two 64-row halves via f32 [64][128] tile, barriered ----
    float* lc = (float*)sm;
#pragma unroll
    for (int half = 0; half < 2; ++half) {
        if (wr == half) {                            // wave-uniform branch
#pragma unroll
            for (int n = 0; n < 4; ++n) {
                const int col = wc * 64 + n * 16 + fr;
#pragma unroll
                for (int m = 0; m < 4; ++m)
#pragma unroll
                    for (int r2 = 0; r2 < 4; ++r2)
                        lc[(m * 16 + fg * 4 + r2) * 128 + col] = acc[m][n][r2];
            }
        }
        __syncthreads();                             // stores visible to all waves
#pragma unroll
        for (int i = 0; i < 8; ++i) {
            const int chunk = i * 256 + tid;         // 2048 chunks = 64x128 / 4
            const int row = chunk >> 5, cb = (chunk & 31) * 4;
            const size_t goff = (size_t)(bm0 + half * 64 + row) * N + bn0 + cb;
            const f32x4 v = ((const f32x4*)lc)[chunk];
            bf16x4 o;
            if (MODE == 1) {
                const bf16x4 bv = *(const bf16x4*)&bias[bn0 + cb];
                const bf16x4 av = *(const bf16x4*)&add[goff];
#pragma unroll
                for (int e = 0; e < 4; ++e) o[e] = (bf16)(v[e] + (float)bv[e] + (float)av[e]);
            } else {
#pragma unroll
                for (int e = 0; e < 4; ++e) o[e] = (bf16)v[e];
            }
            *(bf16x4*)&C[goff] = o;
        }
        __syncthreads();                             // reads done before next half overwrites
    }
}

// ---- attention, T=16: one wave per (seq, head); qs = QKV row stride, os = output row stride ----
__global__ __launch_bounds__(256)
void attn16(const bf16* __restrict__ QKV, bf16* __restrict__ O, int tstride, int lastmul, int qs, int os)
{
    const int lane = threadIdx.x & 63;
    const int gw   = (blockIdx.x * 256 + threadIdx.x) >> 6;
    const int head = gw % 12;
    const int seq  = gw / 12;
    const int b    = seq / 48, r2 = seq % 48;
    const int s    = r2 >> 4, last = r2 & 15;
    const int tbase = b * 768 + s * 256 + last * lastmul;
    const int fr = lane & 15, fg = lane >> 4;

    const size_t rowQ = (size_t)(tbase + fr * tstride) * qs + head * 32 + fg * 8;
    const bf16x8 kf = *(const bf16x8*)(QKV + rowQ + 384);
    const bf16x8 qf = *(const bf16x8*)(QKV + rowQ);
    const f32x4 z = {0.f, 0.f, 0.f, 0.f};
    f32x4 S = __builtin_amdgcn_mfma_f32_16x16x32_bf16(kf, qf, z, 0, 0, 0);

    const float sc = 0.17677669529663687f;
    float mx = fmaxf(fmaxf(S[0], S[1]), fmaxf(S[2], S[3]));
    mx = fmaxf(mx, __shfl_xor(mx, 16));
    mx = fmaxf(mx, __shfl_xor(mx, 32));
    float p[4], sum = 0.f;
#pragma unroll
    for (int r = 0; r < 4; ++r) { p[r] = __expf((S[r] - mx) * sc); sum += p[r]; }
    sum += __shfl_xor(sum, 16);
    sum += __shfl_xor(sum, 32);
    const float inv = 1.f / sum;

    bf16x8 pa;
#pragma unroll
    for (int j = 0; j < 8; ++j) {
        const int srcg = 2 * fg + (j >> 2);
        const float v = __shfl(p[j & 3], fr + 16 * (srcg & 3));
        pa[j] = (bf16)(fg < 2 ? v * inv : 0.f);
    }

#pragma unroll
    for (int t = 0; t < 2; ++t) {
        bf16x8 vf;
#pragma unroll
        for (int j = 0; j < 8; ++j) {
            const int key = fg * 8 + j;
            vf[j] = (fg < 2)
                ? QKV[(size_t)(tbase + key * tstride) * qs + 768 + head * 32 + fr + 16 * t]
                : (bf16)0.f;
        }
        f32x4 o = __builtin_amdgcn_mfma_f32_16x16x32_bf16(pa, vf, z, 0, 0, 0);
#pragma unroll
        for (int r = 0; r < 4; ++r)
            O[(size_t)(tbase + (fg * 4 + r) * tstride) * os + head * 32 + fr + 16 * t] = (bf16)o[r];
    }
}

// ---------------- attention, T=3: one thread per (seq, head) ----------------
__global__ __launch_bounds__(256)
void attn3(const bf16* __restrict__ QKV, bf16* __restrict__ O, int qs, int os)
{
    const int t    = blockIdx.x * 256 + threadIdx.x;
    const int head = t % 12;
    const int seq  = t / 12;
    const int b    = seq >> 8, hw = seq & 255;
    const size_t base  = (size_t)(b * 768 + hw) * qs + head * 32;
    const size_t tstep = (size_t)256 * qs;

    float s[3][3] = {};
#pragma unroll
    for (int c = 0; c < 4; ++c) {
        bf16x8 q[3], k[3];
#pragma unroll
        for (int i = 0; i < 3; ++i) {
            q[i] = *(const bf16x8*)(QKV + base + i * tstep + c * 8);
            k[i] = *(const bf16x8*)(QKV + base + i * tstep + 384 + c * 8);
        }
#pragma unroll
        for (int i = 0; i < 3; ++i)
#pragma unroll
            for (int j = 0; j < 3; ++j) {
                float a = 0.f;
#pragma unroll
                for (int e = 0; e < 8; ++e) a += (float)q[i][e] * (float)k[j][e];
                s[i][j] += a;
            }
    }
    const float sc = 0.17677669529663687f;
    float p[3][3];
#pragma unroll
    for (int i = 0; i < 3; ++i) {
        const float mx = fmaxf(s[i][0], fmaxf(s[i][1], s[i][2]));
        float sum = 0.f;
#pragma unroll
        for (int j = 0; j < 3; ++j) { p[i][j] = __expf((s[i][j] - mx) * sc); sum += p[i][j]; }
        const float inv = 1.f / sum;
#pragma unroll
        for (int j = 0; j < 3; ++j) p[i][j] *= inv;
    }
    const size_t obase = (size_t)(b * 768 + hw) * os + head * 32;
#pragma unroll
    for (int c = 0; c < 4; ++c) {
        bf16x8 v[3];
#pragma unroll
        for (int j = 0; j < 3; ++j) v[j] = *(const bf16x8*)(QKV + base + j * tstep + 768 + c * 8);
#pragma unroll
        for (int i = 0; i < 3; ++i) {
            bf16x8 ov;
#pragma unroll
            for (int e = 0; e < 8; ++e)
                ov[e] = (bf16)(p[i][0] * (float)v[0][e] + p[i][1] * (float)v[1][e] + p[i][2] * (float)v[2][e]);
            *(bf16x8*)(O + obase + (size_t)i * 256 * os + c * 8) = ov;
        }
    }
}

// ---------------- LayerNorm over 384, one wave per token (LN1) ----------------
__global__ __launch_bounds__(256)
void ln_kernel(const bf16* __restrict__ in, bf16* __restrict__ out,
               const bf16* __restrict__ g, const bf16* __restrict__ be, int ntok)
{
    const int w    = (blockIdx.x * 256 + threadIdx.x) >> 6;
    const int lane = threadIdx.x & 63;
    if (w >= ntok) return;
    const bf16* row = in + (size_t)w * 384;
    float x[6], sum = 0.f;
#pragma unroll
    for (int i = 0; i < 6; ++i) { x[i] = (float)row[lane + i * 64]; sum += x[i]; }
#pragma unroll
    for (int o = 32; o >= 1; o >>= 1) sum += __shfl_xor(sum, o);
    const float mu = sum * (1.f / 384.f);
    float vs = 0.f;
#pragma unroll
    for (int i = 0; i < 6; ++i) { const float d = x[i] - mu; vs += d * d; }
#pragma unroll
    for (int o = 32; o >= 1; o >>= 1) vs += __shfl_xor(vs, o);
    const float rstd = rsqrtf(vs * (1.f / 384.f) + 1e-5f);
    bf16* orow = out + (size_t)w * 384;
#pragma unroll
    for (int i = 0; i < 6; ++i)
        orow[lane + i * 64] = (bf16)((x[i] - mu) * rstd * (float)g[lane + i * 64] + (float)be[lane + i * 64]);
}

// ======== fused LN2 + output transpose (PROVEN R20) ========
__global__ __launch_bounds__(256)
void ln_transpose_out(const bf16* __restrict__ in, void* out, size_t base_off,
                      const bf16* __restrict__ g, const bf16* __restrict__ be, const int* flag)
{
    __shared__ bf16 tile[32][388];                  // pad 388 -> 2-way bank conflict (free)
    const int f32 = *flag;
    const int tid = threadIdx.x;
    const int lane = tid & 63, w = tid >> 6;        // wave 0..3
    const int r0 = blockIdx.x * 32;                 // token window within batch image
    const int zz = blockIdx.y;
    const bf16* inz = in + ((size_t)zz * 768 + r0) * 384;

#pragma unroll
    for (int p = 0; p < 8; ++p) {                   // 8 passes x 4 waves = 32 tokens
        const int tok = p * 4 + w;
        const bf16* row = inz + (size_t)tok * 384;
        float x[6], sum = 0.f;
#pragma unroll
        for (int i = 0; i < 6; ++i) { x[i] = (float)row[lane + i * 64]; sum += x[i]; }
#pragma unroll
        for (int o = 32; o >= 1; o >>= 1) sum += __shfl_xor(sum, o);
        const float mu = sum * (1.f / 384.f);
        float vs = 0.f;
#pragma unroll
        for (int i = 0; i < 6; ++i) { const float d = x[i] - mu; vs += d * d; }
#pragma unroll
        for (int o = 32; o >= 1; o >>= 1) vs += __shfl_xor(vs, o);
        const float rstd = rsqrtf(vs * (1.f / 384.f) + 1e-5f);
#pragma unroll
        for (int i = 0; i < 6; ++i)
            tile[tok][lane + i * 64] =
                (bf16)((x[i] - mu) * rstd * (float)g[lane + i * 64] + (float)be[lane + i * 64]);
    }
    __syncthreads();

    // transposed write: out[z][c][768], cols r0..r0+31
    const size_t bo = base_off + (size_t)zz * 384 * 768;
#pragma unroll
    for (int it = 0; it < 48; ++it) {               // 384*32 / 256
        const int idx = it * 256 + tid;
        const int c = idx >> 5, r = idx & 31;
        const u16 v = __builtin_bit_cast(u16, tile[r][c]);
        const size_t o = bo + (size_t)c * 768 + r0 + r;
        if (f32) ((float*)out)[o] = b2f(v); else ((u16*)out)[o] = v;
    }
}

// ---------------- launch ----------------
extern "C" void kernel_launch(void* const* d_in, const int* in_sizes, int n_in,
                              void* d_out, int out_size, void* d_ws, size_t ws_size,
                              hipStream_t stream)
{
    const void* x = d_in[0];
    const void *Wq[3], *Wkv[3], *Wo[3], *bo[3];
    for (int i = 0; i < 3; ++i) {
        Wq[i]  = d_in[1 + 4 * i];
        Wkv[i] = d_in[2 + 4 * i];
        Wo[i]  = d_in[3 + 4 * i];
        bo[i]  = d_in[4 + 4 * i];
    }
    const void* g1  = d_in[13];
    const void* be1 = d_in[14];
    const void* W1m = d_in[15];
    const void* b1m = d_in[16];
    const void* W2m = d_in[17];
    const void* b2m = d_in[18];
    const void* g2  = d_in[19];
    const void* be2 = d_in[20];

    // ---- workspace layout (element offsets match wtrans_all's DOarr) ----
    char* ws = (char*)d_ws;
    bf16* qkvT = (bf16*)(ws);                       // [3456][384] per-axis QKV weights (i*1152 rows)
    bf16* woTf = (bf16*)(ws + 2654208ull);          // [384][1152] stacked O-proj weights
    bf16* w1mT = (bf16*)(ws + 3538944ull);          // [1536][384]
    bf16* w2mT = (bf16*)(ws + 4718592ull);          // [384][1536]
    bf16* vp   = (bf16*)(ws + 5898240ull);          // 3840 bf16: vboS,vg1,vbe1,vg2,vbe2,vb1m,vb2m
    bf16* vboS = vp;
    bf16* vg1  = vp + 384;  bf16* vbe1 = vp + 768;
    bf16* vg2  = vp + 1152; bf16* vbe2 = vp + 1536;
    bf16* vb1m = vp + 1920; bf16* vb2m = vp + 3456;
    int* dflag = (int*)(ws + 5909504ull);
    const size_t WB = 6553600ull;                   // chunk region base

    // chunk size: NB=32 (4 chunks); live set during QKV/attn ~132MB -> L3-resident
    int NB = 32;
    while (NB > 2) {
        size_t need = WB + (size_t)NB * 768 * (3 * 384 + 2 * 1152 + 1536) * 2;
        if (need <= ws_size) break;
        NB >>= 1;
    }
    const int Tc = NB * 768;
    const size_t tokB = (size_t)Tc * 384 * 2;
    bf16* Xc    = (bf16*)(ws + WB);
    bf16* ABc   = (bf16*)(ws + WB + tokB);
    bf16* T1c   = (bf16*)(ws + WB + 2 * tokB);
    bf16* ATOc  = (bf16*)(ws + WB + 3 * tokB);      // Tc x 1152 (3 axes side by side)
    bf16* QKVc  = (bf16*)(ws + WB + 6 * tokB);      // Tc x 1152 (one axis at a time)
    bf16* BIGc  = (bf16*)(ws + WB + 9 * tokB);      // Tc x 1536 (MLP hidden)

    // ---- consolidated setup: probe + 1 vector-cvt + 1 batched weight transpose ----
    probe_dtype<<<1, 256, 0, stream>>>((const float*)x, dflag);
    cvt_all<<<15, 256, 0, stream>>>(bo[0], bo[1], bo[2], g1, be1, g2, be2, b1m, b2m, vp, dflag);
    SrcPtrs sp;
    sp.p[0] = Wq[0]; sp.p[1] = Wkv[0]; sp.p[2] = Wo[0];
    sp.p[3] = Wq[1]; sp.p[4] = Wkv[1]; sp.p[5] = Wo[1];
    sp.p[6] = Wq[2]; sp.p[7] = Wkv[2]; sp.p[8] = Wo[2];
    sp.p[9] = W1m;   sp.p[10] = W2m;
    wtrans_all<<<2880, 256, 0, stream>>>(sp, (u16*)ws, dflag);

    const dim3 tb(32, 8);
    for (int b0 = 0; b0 < 128; b0 += NB) {
        const size_t xoff = (size_t)b0 * 384 * 768;
        transpose_cvt<<<dim3(24, 12, NB), tb, 0, stream>>>(x, (u16*)Xc, xoff, 384, 768, 384, dflag);

        // per-axis QKV (small L3-resident buffer) + attention into shared ATOc columns
        for (int i = 0; i < 3; ++i) {
            gemm_bt<0><<<dim3(Tc / 128, 9), 256, 0, stream>>>(Xc, qkvT + (size_t)(i * 1152) * 384,
                                                              QKVc, nullptr, nullptr, Tc, 1152, 384);
            if (i == 0)      attn3 <<<NB * 12,  256, 0, stream>>>(QKVc, ATOc,              1152, 1152);
            else if (i == 1) attn16<<<NB * 144, 256, 0, stream>>>(QKVc, ATOc + 384, 16, 1, 1152, 1152);
            else             attn16<<<NB * 144, 256, 0, stream>>>(QKVc, ATOc + 768, 1, 16, 1152, 1152);
        }

        // fused O-projection: sum over 3 axes in one K=1152 GEMM (+ Sum(bo) + residual Xc)
        gemm_bt<1><<<dim3(Tc / 128, 3), 256, 0, stream>>>(ATOc, woTf, ABc, vboS, Xc, Tc, 384, 1152);

        ln_kernel<<<Tc / 4, 256, 0, stream>>>(ABc, T1c, vg1, vbe1, Tc);
        gemm256<2><<<dim3(Tc / 256, 6), 512, 0, stream>>>(T1c, w1mT, BIGc, vb1m, Tc, 1536, 384);
        gemm_bt<1><<<dim3(Tc / 128, 3), 256, 0, stream>>>(BIGc, w2mT, ABc, vb2m, T1c, Tc, 384, 1536);
        // fused LN2 + transpose straight to d_out (saves the Xc round-trip)
        ln_transpose_out<<<dim3(24, NB), 256, 0, stream>>>(ABc, d_out, xoff, vg2, vbe2, dflag);
    }
}

// Round 22
// 1428.214 us; speedup vs baseline: 1.0685x; 1.0141x over previous
//
#include <hip/hip_runtime.h>

typedef unsigned short u16;
typedef __bf16 bf16;
typedef bf16  bf16x4 __attribute__((ext_vector_type(4)));
typedef bf16  bf16x8 __attribute__((ext_vector_type(8)));
typedef float f32x4  __attribute__((ext_vector_type(4)));

__device__ __forceinline__ u16  f2b(float v) { return __builtin_bit_cast(u16, (bf16)v); }
__device__ __forceinline__ float b2f(u16 b)  { return (float)__builtin_bit_cast(bf16, b); }

// ---------------- dtype probe: flag=1 if float inputs are f32, 0 if bf16 ----------------
__global__ void probe_dtype(const float* xf, int* flag) {
    __shared__ int cnt[256];
    const int tid = threadIdx.x;
    int good = 0;
#pragma unroll
    for (int i = 0; i < 4; ++i) {
        const float a = fabsf(xf[tid * 4 + i]);
        if (a > 9.5e-7f && a < 1.0e6f) good++;   // NaN fails both
    }
    cnt[tid] = good;
    __syncthreads();
    if (tid == 0) { int s = 0; for (int i = 0; i < 256; ++i) s += cnt[i]; *flag = (s > 512) ? 1 : 0; }
}

__device__ __forceinline__ float rd_flag(const void* p, int i, int f32) {
    return f32 ? ((const float*)p)[i] : b2f(((const u16*)p)[i]);
}

// ======== consolidated small-vector conversion (PROVEN R21) ========
__global__ __launch_bounds__(256)
void cvt_all(const void* bo0, const void* bo1, const void* bo2,
             const void* g1, const void* be1, const void* g2, const void* be2,
             const void* b1m, const void* b2m, bf16* vp, const int* flag)
{
    const int f32 = *flag;
    const int i = blockIdx.x * 256 + threadIdx.x;   // 15 blocks x 256 = 3840
    if (i < 384) {
        vp[i] = (bf16)(rd_flag(bo0, i, f32) + rd_flag(bo1, i, f32) + rd_flag(bo2, i, f32));
    } else if (i < 768)  { vp[i] = (bf16)rd_flag(g1,  i - 384,  f32); }
    else if (i < 1152)   { vp[i] = (bf16)rd_flag(be1, i - 768,  f32); }
    else if (i < 1536)   { vp[i] = (bf16)rd_flag(g2,  i - 1152, f32); }
    else if (i < 1920)   { vp[i] = (bf16)rd_flag(be2, i - 1536, f32); }
    else if (i < 3456)   { vp[i] = (bf16)rd_flag(b1m, i - 1920, f32); }
    else                 { vp[i] = (bf16)rd_flag(b2m, i - 3456, f32); }
}

// ======== consolidated weight transposes (PROVEN R21) ========
struct SrcPtrs { const void* p[11]; };
__global__ __launch_bounds__(256)
void wtrans_all(SrcPtrs srcs, u16* wsbase, const int* flag)
{
    const int prefix[12] = {0, 144, 432, 576, 720, 1008, 1152, 1296, 1584, 1728, 2304, 2880};
    const int Carr[11]   = {384, 768, 384,  384, 768, 384,  384, 768, 384,  1536, 384};
    const int OSarr[11]  = {384, 384, 1152, 384, 384, 1152, 384, 384, 1152, 384, 1536};
    const int DOarr[11]  = {0, 147456, 1327104, 442368, 589824, 1327488,
                            884736, 1032192, 1327872, 1769472, 2359296};

    __shared__ u16 tile[32][34];
    const int f32 = *flag;
    const int bid = blockIdx.x;
    int s = 0;
#pragma unroll
    for (int k = 0; k < 11; ++k) if (bid >= prefix[k + 1]) s = k + 1;
    const int tix = bid - prefix[s];
    const int C = Carr[s], ostride = OSarr[s];
    const int tilesX = C >> 5;
    const int c0 = (tix % tilesX) * 32, r0 = (tix / tilesX) * 32;
    const void* in = srcs.p[s];
    u16* out = wsbase + DOarr[s];

    const int tx = threadIdx.x & 31, ty = threadIdx.x >> 5;   // 32 x 8
#pragma unroll
    for (int i = 0; i < 4; ++i) {
        const int idx = (r0 + ty + i * 8) * C + c0 + tx;
        tile[ty + i * 8][tx] = f32 ? f2b(((const float*)in)[idx]) : ((const u16*)in)[idx];
    }
    __syncthreads();
#pragma unroll
    for (int i = 0; i < 4; ++i)
        out[(size_t)(c0 + ty + i * 8) * ostride + r0 + tx] = tile[tx][ty + i * 8];
}

// ---- transpose + convert: in[z][R][C] (flag dtype) -> out[z][C][ostride] bf16 (input x) ----
__global__ void transpose_cvt(const void* in, u16* out, size_t base_off, int R, int C, int ostride, const int* flag) {
    __shared__ u16 tile[32][34];
    const int f32 = *flag;
    const int c0 = blockIdx.x * 32, r0 = blockIdx.y * 32;
    const size_t bi = base_off + (size_t)blockIdx.z * R * C;
    const size_t bo = (size_t)blockIdx.z * C * ostride;
    const int tx = threadIdx.x, ty = threadIdx.y;
#pragma unroll
    for (int i = 0; i < 4; ++i) {
        const size_t idx = bi + (size_t)(r0 + ty + i * 8) * C + c0 + tx;
        tile[ty + i * 8][tx] = f32 ? f2b(((const float*)in)[idx]) : ((const u16*)in)[idx];
    }
    __syncthreads();
#pragma unroll
    for (int i = 0; i < 4; ++i)
        out[bo + (size_t)(c0 + ty + i * 8) * ostride + r0 + tx] = tile[tx][ty + i * 8];
}

// ---------------- global -> LDS async staging (16B/lane) ----------------
__device__ __forceinline__ void gld_lds16(const bf16* g, bf16* l) {
    __builtin_amdgcn_global_load_lds((__attribute__((address_space(1))) void*)g,
                                     (__attribute__((address_space(3))) void*)l,
                                     16, 0, 0);
}

// ---------------- GEMM 256x256, 8 waves, 2-phase dbuf, swizzled LDS (PROVEN R5-R21) ----------------
// MODE 0: C = acc ; MODE 2: C = gelu(acc + bias[n])
template<int MODE>
__global__ __launch_bounds__(512)
void gemm256(const bf16* __restrict__ A, const bf16* __restrict__ BT,
             bf16* C, const bf16* __restrict__ bias, int M, int N, int K)
{
    __shared__ __align__(16) bf16 sm[65536];        // 128 KB
    const int tid = threadIdx.x;

    const int gx = gridDim.x, gy = gridDim.y;
    int lin = blockIdx.y * gx + blockIdx.x;
    const int nwg = gx * gy;
    const int q = nwg >> 3, r8 = nwg & 7;
    const int xcd = lin & 7, idx = lin >> 3;
    lin = (xcd < r8 ? xcd * (q + 1) : r8 * (q + 1) + (xcd - r8) * q) + idx;
    const int bm0 = (lin / gy) * 256;
    const int bn0 = (lin % gy) * 256;

    const int lane = tid & 63, wid = tid >> 6;
    const int wr = wid >> 2, wc = wid & 3;           // 2x4 waves, wave tile 128x64
    const int fr = lane & 15, fg = lane >> 4;
    const int arow = tid >> 3;                       // 0..63
    const int scol = ((tid & 7) ^ (arow & 7)) << 3;  // pre-swizzled source col

    const bf16* Ab = A  + (size_t)(bm0 + arow) * K + scol;
    const bf16* Bb = BT + (size_t)(bn0 + arow) * K + scol;

    bf16* const lA0 = sm;
    bf16* const lA1 = sm + 16384;
    bf16* const lB0 = sm + 32768;
    bf16* const lB1 = sm + 49152;

    f32x4 acc[8][4] = {};
    const int NT = K >> 6;

#pragma unroll
    for (int i = 0; i < 4; ++i) gld_lds16(Ab + (size_t)i * 64 * K, lA0 + i * 4096 + tid * 8);
#pragma unroll
    for (int i = 0; i < 4; ++i) gld_lds16(Bb + (size_t)i * 64 * K, lB0 + i * 4096 + tid * 8);
    __syncthreads();

    const int sw = fr & 7;
    for (int t = 0; t < NT; ++t) {
        if (t + 1 < NT) {
            const int k0 = (t + 1) << 6;
            bf16* la = ((t + 1) & 1) ? lA1 : lA0;
            bf16* lb = ((t + 1) & 1) ? lB1 : lB0;
#pragma unroll
            for (int i = 0; i < 4; ++i) gld_lds16(Ab + k0 + (size_t)i * 64 * K, la + i * 4096 + tid * 8);
#pragma unroll
            for (int i = 0; i < 4; ++i) gld_lds16(Bb + k0 + (size_t)i * 64 * K, lb + i * 4096 + tid * 8);
        }
        const bf16* la = (t & 1) ? lA1 : lA0;
        const bf16* lb = (t & 1) ? lB1 : lB0;
#pragma unroll
        for (int kk = 0; kk < 2; ++kk) {
            const int so = ((((kk << 2) + fg) ^ sw) << 3);
            bf16x8 bfv[4];
#pragma unroll
            for (int n = 0; n < 4; ++n)
                bfv[n] = *(const bf16x8*)&lb[(wc * 64 + n * 16 + fr) * 64 + so];
#pragma unroll
            for (int m = 0; m < 8; ++m) {
                const bf16x8 af = *(const bf16x8*)&la[(wr * 128 + m * 16 + fr) * 64 + so];
#pragma unroll
                for (int n = 0; n < 4; ++n)
                    acc[m][n] = __builtin_amdgcn_mfma_f32_16x16x32_bf16(af, bfv[n], acc[m][n], 0, 0, 0);
            }
        }
        __syncthreads();
    }

    // epilogue: acc (+bias/gelu) -> LDS bf16 [256][256] -> coalesced 16B stores
#pragma unroll
    for (int n = 0; n < 4; ++n) {
        const int col = wc * 64 + n * 16 + fr;
        const float bv = (MODE == 2) ? (float)bias[bn0 + col] : 0.f;
#pragma unroll
        for (int m = 0; m < 8; ++m) {
            const int row0 = wr * 128 + m * 16 + fg * 4;
#pragma unroll
            for (int r = 0; r < 4; ++r) {
                float v = acc[m][n][r];
                if (MODE == 2) { v += bv; v = 0.5f * v * (1.f + erff(v * 0.70710678118654752f)); }
                sm[(row0 + r) * 256 + col] = (bf16)v;
            }
        }
    }
    __syncthreads();
#pragma unroll
    for (int it = 0; it < 16; ++it) {
        const int chunk = it * 512 + tid;
        const int row = chunk >> 5, c8 = (chunk & 31) << 3;
        *(bf16x8*)&C[(size_t)(bm0 + row) * N + bn0 + c8] = *(const bf16x8*)&sm[row * 256 + c8];
    }
}

// ======== GEMM 128x128: SINGLE-buffer m97 2-barrier loop, 32KB LDS (PROVEN R13-R21) ========
// MODE 0: C = acc ; MODE 1: C = acc + bias[n] + add[m,n]
template<int MODE>
__global__ __launch_bounds__(256)
void gemm_bt(const bf16* __restrict__ A, const bf16* __restrict__ BT,
             bf16* C, const bf16* __restrict__ bias,
             const bf16* add, int M, int N, int K)
{
    __shared__ __align__(16) bf16 sm[16384];         // 32 KB: stage A(16KB)+B(16KB); epi: f32 64x128
    const int tid = threadIdx.x;

    const int gx = gridDim.x, gy = gridDim.y;
    int lin = blockIdx.y * gx + blockIdx.x;
    const int nwg = gx * gy;
    const int q = nwg >> 3, r8 = nwg & 7;
    const int xcd = lin & 7, idx = lin >> 3;
    lin = (xcd < r8 ? xcd * (q + 1) : r8 * (q + 1) + (xcd - r8) * q) + idx;
    const int bm0 = (lin / gy) * 128;
    const int bn0 = (lin % gy) * 128;

    const int lane = tid & 63, wid = tid >> 6;
    const int wr = wid >> 1, wc = wid & 1;           // 2x2 waves, wave tile 64x64
    const int fr = lane & 15, fg = lane >> 4;
    const int arow = tid >> 3;                       // 0..31
    const int scol = ((tid & 7) ^ (arow & 7)) << 3;

    const bf16* Ab = A  + (size_t)(bm0 + arow) * K + scol;
    const bf16* Bb = BT + (size_t)(bn0 + arow) * K + scol;

    bf16* const lA = sm;                             // 128x64
    bf16* const lB = sm + 8192;

    f32x4 acc[4][4] = {};
    const int NT = K >> 6;
    const int sw = fr & 7;

    for (int t = 0; t < NT; ++t) {
        __syncthreads();                             // WAR: previous compute reads retired
        const int k0 = t << 6;
#pragma unroll
        for (int i = 0; i < 4; ++i) gld_lds16(Ab + k0 + (size_t)i * 32 * K, lA + i * 2048 + tid * 8);
#pragma unroll
        for (int i = 0; i < 4; ++i) gld_lds16(Bb + k0 + (size_t)i * 32 * K, lB + i * 2048 + tid * 8);
        __syncthreads();                             // RAW: vmcnt drained, stage visible
#pragma unroll
        for (int kk = 0; kk < 2; ++kk) {
            bf16x8 af[4], bfv[4];
#pragma unroll
            for (int m = 0; m < 4; ++m)
                af[m] = *(const bf16x8*)&lA[(wr * 64 + m * 16 + fr) * 64 + ((((kk << 2) + fg) ^ sw) << 3)];
#pragma unroll
            for (int n = 0; n < 4; ++n)
                bfv[n] = *(const bf16x8*)&lB[(wc * 64 + n * 16 + fr) * 64 + ((((kk << 2) + fg) ^ sw) << 3)];
#pragma unroll
            for (int m = 0; m < 4; ++m)
#pragma unroll
                for (int n = 0; n < 4; ++n)
                    acc[m][n] = __builtin_amdgcn_mfma_f32_16x16x32_bf16(af[m], bfv[n], acc[m][n], 0, 0, 0);
        }
    }
    __syncthreads();                                 // all compute reads done before epi reuse

    // ---- epilogue: two 64-row halves via f32 [64][128] tile, barriered ----
    float* lc = (float*)sm;
#pragma unroll
    for (int half = 0; half < 2; ++half) {
        if (wr == half) {                            // wave-uniform branch
#pragma unroll
            for (int n = 0; n < 4; ++n) {
                const int col = wc * 64 + n * 16 + fr;
#pragma unroll
                for (int m = 0; m < 4; ++m)
#pragma unroll
                    for (int r2 = 0; r2 < 4; ++r2)
                        lc[(m * 16 + fg * 4 + r2) * 128 + col] = acc[m][n][r2];
            }
        }
        __syncthreads();                             // stores visible to all waves
#pragma unroll
        for (int i = 0; i < 8; ++i) {
            const int chunk = i * 256 + tid;         // 2048 chunks = 64x128 / 4
            const int row = chunk >> 5, cb = (chunk & 31) * 4;
            const size_t goff = (size_t)(bm0 + half * 64 + row) * N + bn0 + cb;
            const f32x4 v = ((const f32x4*)lc)[chunk];
            bf16x4 o;
            if (MODE == 1) {
                const bf16x4 bv = *(const bf16x4*)&bias[bn0 + cb];
                const bf16x4 av = *(const bf16x4*)&add[goff];
#pragma unroll
                for (int e = 0; e < 4; ++e) o[e] = (bf16)(v[e] + (float)bv[e] + (float)av[e]);
            } else {
#pragma unroll
                for (int e = 0; e < 4; ++e) o[e] = (bf16)v[e];
            }
            *(bf16x4*)&C[goff] = o;
        }
        __syncthreads();                             // reads done before next half overwrites
    }
}

// ==== attention, T=16, LDS-staged: one block per seq; 12 waves = 12 heads (math = PROVEN attn16) ====
__global__ __launch_bounds__(768)
void attn16_lds(const bf16* __restrict__ QKV, bf16* __restrict__ O, int tstride, int lastmul, int qs, int os)
{
    __shared__ bf16 kv[16 * 1160];                  // 16 tokens x 1152 (+8 pad) = 36.25 KB
    const int tid  = threadIdx.x;
    const int lane = tid & 63, h = tid >> 6;        // wave = head 0..11
    const int seq  = blockIdx.x;
    const int b    = seq / 48, r2 = seq % 48;
    const int s    = r2 >> 4, last = r2 & 15;
    const int tbase = b * 768 + s * 256 + last * lastmul;
    const int fr = lane & 15, fg = lane >> 4;

    // cooperative stage: 2304 bf16x8 chunks over 768 threads (3 each), coalesced rows
#pragma unroll
    for (int k = 0; k < 3; ++k) {
        const int c = k * 768 + tid;
        const int row = c / 144, col = (c % 144) * 8;
        *(bf16x8*)&kv[row * 1160 + col] =
            *(const bf16x8*)&QKV[(size_t)(tbase + row * tstride) * qs + col];
    }
    __syncthreads();

    const bf16* base = kv + h * 32;
    const bf16x8 qf = *(const bf16x8*)&base[fr * 1160 + fg * 8];
    const bf16x8 kf = *(const bf16x8*)&base[fr * 1160 + 384 + fg * 8];
    const f32x4 z = {0.f, 0.f, 0.f, 0.f};
    // swapped: S'[key = fg*4+r][q = fr]
    f32x4 S = __builtin_amdgcn_mfma_f32_16x16x32_bf16(kf, qf, z, 0, 0, 0);

    const float sc = 0.17677669529663687f;
    float mx = fmaxf(fmaxf(S[0], S[1]), fmaxf(S[2], S[3]));
    mx = fmaxf(mx, __shfl_xor(mx, 16));
    mx = fmaxf(mx, __shfl_xor(mx, 32));
    float p[4], sum = 0.f;
#pragma unroll
    for (int r = 0; r < 4; ++r) { p[r] = __expf((S[r] - mx) * sc); sum += p[r]; }
    sum += __shfl_xor(sum, 16);
    sum += __shfl_xor(sum, 32);
    const float inv = 1.f / sum;

    bf16x8 pa;
#pragma unroll
    for (int j = 0; j < 8; ++j) {
        const int srcg = 2 * fg + (j >> 2);
        const float v = __shfl(p[j & 3], fr + 16 * (srcg & 3));
        pa[j] = (bf16)(fg < 2 ? v * inv : 0.f);
    }

#pragma unroll
    for (int t = 0; t < 2; ++t) {
        bf16x8 vf;
#pragma unroll
        for (int j = 0; j < 8; ++j) {
            const int key = fg * 8 + j;                  // valid (<16) iff fg<2
            vf[j] = (fg < 2) ? base[key * 1160 + 768 + fr + 16 * t] : (bf16)0.f;
        }
        f32x4 o = __builtin_amdgcn_mfma_f32_16x16x32_bf16(pa, vf, z, 0, 0, 0);
#pragma unroll
        for (int r = 0; r < 4; ++r)
            O[(size_t)(tbase + (fg * 4 + r) * tstride) * os + h * 32 + fr + 16 * t] = (bf16)o[r];
    }
}

// ---------------- attention, T=3: one thread per (seq, head) (PROVEN) ----------------
__global__ __launch_bounds__(256)
void attn3(const bf16* __restrict__ QKV, bf16* __restrict__ O, int qs, int os)
{
    const int t    = blockIdx.x * 256 + threadIdx.x;
    const int head = t % 12;
    const int seq  = t / 12;
    const int b    = seq >> 8, hw = seq & 255;
    const size_t base  = (size_t)(b * 768 + hw) * qs + head * 32;
    const size_t tstep = (size_t)256 * qs;

    float s[3][3] = {};
#pragma unroll
    for (int c = 0; c < 4; ++c) {
        bf16x8 q[3], k[3];
#pragma unroll
        for (int i = 0; i < 3; ++i) {
            q[i] = *(const bf16x8*)(QKV + base + i * tstep + c * 8);
            k[i] = *(const bf16x8*)(QKV + base + i * tstep + 384 + c * 8);
        }
#pragma unroll
        for (int i = 0; i < 3; ++i)
#pragma unroll
            for (int j = 0; j < 3; ++j) {
                float a = 0.f;
#pragma unroll
                for (int e = 0; e < 8; ++e) a += (float)q[i][e] * (float)k[j][e];
                s[i][j] += a;
            }
    }
    const float sc = 0.17677669529663687f;
    float p[3][3];
#pragma unroll
    for (int i = 0; i < 3; ++i) {
        const float mx = fmaxf(s[i][0], fmaxf(s[i][1], s[i][2]));
        float sum = 0.f;
#pragma unroll
        for (int j = 0; j < 3; ++j) { p[i][j] = __expf((s[i][j] - mx) * sc); sum += p[i][j]; }
        const float inv = 1.f / sum;
#pragma unroll
        for (int j = 0; j < 3; ++j) p[i][j] *= inv;
    }
    const size_t obase = (size_t)(b * 768 + hw) * os + head * 32;
#pragma unroll
    for (int c = 0; c < 4; ++c) {
        bf16x8 v[3];
#pragma unroll
        for (int j = 0; j < 3; ++j) v[j] = *(const bf16x8*)(QKV + base + j * tstep + 768 + c * 8);
#pragma unroll
        for (int i = 0; i < 3; ++i) {
            bf16x8 ov;
#pragma unroll
            for (int e = 0; e < 8; ++e)
                ov[e] = (bf16)(p[i][0] * (float)v[0][e] + p[i][1] * (float)v[1][e] + p[i][2] * (float)v[2][e]);
            *(bf16x8*)(O + obase + (size_t)i * 256 * os + c * 8) = ov;
        }
    }
}

// ---------------- LayerNorm over 384, one wave per token (LN1) ----------------
__global__ __launch_bounds__(256)
void ln_kernel(const bf16* __restrict__ in, bf16* __restrict__ out,
               const bf16* __restrict__ g, const bf16* __restrict__ be, int ntok)
{
    const int w    = (blockIdx.x * 256 + threadIdx.x) >> 6;
    const int lane = threadIdx.x & 63;
    if (w >= ntok) return;
    const bf16* row = in + (size_t)w * 384;
    float x[6], sum = 0.f;
#pragma unroll
    for (int i = 0; i < 6; ++i) { x[i] = (float)row[lane + i * 64]; sum += x[i]; }
#pragma unroll
    for (int o = 32; o >= 1; o >>= 1) sum += __shfl_xor(sum, o);
    const float mu = sum * (1.f / 384.f);
    float vs = 0.f;
#pragma unroll
    for (int i = 0; i < 6; ++i) { const float d = x[i] - mu; vs += d * d; }
#pragma unroll
    for (int o = 32; o >= 1; o >>= 1) vs += __shfl_xor(vs, o);
    const float rstd = rsqrtf(vs * (1.f / 384.f) + 1e-5f);
    bf16* orow = out + (size_t)w * 384;
#pragma unroll
    for (int i = 0; i < 6; ++i)
        orow[lane + i * 64] = (bf16)((x[i] - mu) * rstd * (float)g[lane + i * 64] + (float)be[lane + i * 64]);
}

// ======== fused LN2 + output transpose (PROVEN R20/R21) ========
__global__ __launch_bounds__(256)
void ln_transpose_out(const bf16* __restrict__ in, void* out, size_t base_off,
                      const bf16* __restrict__ g, const bf16* __restrict__ be, const int* flag)
{
    __shared__ bf16 tile[32][388];                  // pad 388 -> 2-way bank conflict (free)
    const int f32 = *flag;
    const int tid = threadIdx.x;
    const int lane = tid & 63, w = tid >> 6;        // wave 0..3
    const int r0 = blockIdx.x * 32;                 // token window within batch image
    const int zz = blockIdx.y;
    const bf16* inz = in + ((size_t)zz * 768 + r0) * 384;

#pragma unroll
    for (int p = 0; p < 8; ++p) {                   // 8 passes x 4 waves = 32 tokens
        const int tok = p * 4 + w;
        const bf16* row = inz + (size_t)tok * 384;
        float x[6], sum = 0.f;
#pragma unroll
        for (int i = 0; i < 6; ++i) { x[i] = (float)row[lane + i * 64]; sum += x[i]; }
#pragma unroll
        for (int o = 32; o >= 1; o >>= 1) sum += __shfl_xor(sum, o);
        const float mu = sum * (1.f / 384.f);
        float vs = 0.f;
#pragma unroll
        for (int i = 0; i < 6; ++i) { const float d = x[i] - mu; vs += d * d; }
#pragma unroll
        for (int o = 32; o >= 1; o >>= 1) vs += __shfl_xor(vs, o);
        const float rstd = rsqrtf(vs * (1.f / 384.f) + 1e-5f);
#pragma unroll
        for (int i = 0; i < 6; ++i)
            tile[tok][lane + i * 64] =
                (bf16)((x[i] - mu) * rstd * (float)g[lane + i * 64] + (float)be[lane + i * 64]);
    }
    __syncthreads();

    // transposed write: out[z][c][768], cols r0..r0+31
    const size_t bo = base_off + (size_t)zz * 384 * 768;
#pragma unroll
    for (int it = 0; it < 48; ++it) {               // 384*32 / 256
        const int idx = it * 256 + tid;
        const int c = idx >> 5, r = idx & 31;
        const u16 v = __builtin_bit_cast(u16, tile[r][c]);
        const size_t o = bo + (size_t)c * 768 + r0 + r;
        if (f32) ((float*)out)[o] = b2f(v); else ((u16*)out)[o] = v;
    }
}

// ---------------- launch ----------------
extern "C" void kernel_launch(void* const* d_in, const int* in_sizes, int n_in,
                              void* d_out, int out_size, void* d_ws, size_t ws_size,
                              hipStream_t stream)
{
    const void* x = d_in[0];
    const void *Wq[3], *Wkv[3], *Wo[3], *bo[3];
    for (int i = 0; i < 3; ++i) {
        Wq[i]  = d_in[1 + 4 * i];
        Wkv[i] = d_in[2 + 4 * i];
        Wo[i]  = d_in[3 + 4 * i];
        bo[i]  = d_in[4 + 4 * i];
    }
    const void* g1  = d_in[13];
    const void* be1 = d_in[14];
    const void* W1m = d_in[15];
    const void* b1m = d_in[16];
    const void* W2m = d_in[17];
    const void* b2m = d_in[18];
    const void* g2  = d_in[19];
    const void* be2 = d_in[20];

    // ---- workspace layout (element offsets match wtrans_all's DOarr) ----
    char* ws = (char*)d_ws;
    bf16* qkvT = (bf16*)(ws);                       // [3456][384] per-axis QKV weights (i*1152 rows)
    bf16* woTf = (bf16*)(ws + 2654208ull);          // [384][1152] stacked O-proj weights
    bf16* w1mT = (bf16*)(ws + 3538944ull);          // [1536][384]
    bf16* w2mT = (bf16*)(ws + 4718592ull);          // [384][1536]
    bf16* vp   = (bf16*)(ws + 5898240ull);          // 3840 bf16: vboS,vg1,vbe1,vg2,vbe2,vb1m,vb2m
    bf16* vboS = vp;
    bf16* vg1  = vp + 384;  bf16* vbe1 = vp + 768;
    bf16* vg2  = vp + 1152; bf16* vbe2 = vp + 1536;
    bf16* vb1m = vp + 1920; bf16* vb2m = vp + 3456;
    int* dflag = (int*)(ws + 5909504ull);
    const size_t WB = 6553600ull;                   // chunk region base

    // chunk size: NB=32 (4 chunks); live set during QKV/attn ~132MB -> L3-resident
    int NB = 32;
    while (NB > 2) {
        size_t need = WB + (size_t)NB * 768 * (3 * 384 + 2 * 1152 + 1536) * 2;
        if (need <= ws_size) break;
        NB >>= 1;
    }
    const int Tc = NB * 768;
    const size_t tokB = (size_t)Tc * 384 * 2;
    bf16* Xc    = (bf16*)(ws + WB);
    bf16* ABc   = (bf16*)(ws + WB + tokB);
    bf16* T1c   = (bf16*)(ws + WB + 2 * tokB);
    bf16* ATOc  = (bf16*)(ws + WB + 3 * tokB);      // Tc x 1152 (3 axes side by side)
    bf16* QKVc  = (bf16*)(ws + WB + 6 * tokB);      // Tc x 1152 (one axis at a time)
    bf16* BIGc  = (bf16*)(ws + WB + 9 * tokB);      // Tc x 1536 (MLP hidden)

    // ---- consolidated setup: probe + 1 vector-cvt + 1 batched weight transpose ----
    probe_dtype<<<1, 256, 0, stream>>>((const float*)x, dflag);
    cvt_all<<<15, 256, 0, stream>>>(bo[0], bo[1], bo[2], g1, be1, g2, be2, b1m, b2m, vp, dflag);
    SrcPtrs sp;
    sp.p[0] = Wq[0]; sp.p[1] = Wkv[0]; sp.p[2] = Wo[0];
    sp.p[3] = Wq[1]; sp.p[4] = Wkv[1]; sp.p[5] = Wo[1];
    sp.p[6] = Wq[2]; sp.p[7] = Wkv[2]; sp.p[8] = Wo[2];
    sp.p[9] = W1m;   sp.p[10] = W2m;
    wtrans_all<<<2880, 256, 0, stream>>>(sp, (u16*)ws, dflag);

    const dim3 tb(32, 8);
    for (int b0 = 0; b0 < 128; b0 += NB) {
        const size_t xoff = (size_t)b0 * 384 * 768;
        transpose_cvt<<<dim3(24, 12, NB), tb, 0, stream>>>(x, (u16*)Xc, xoff, 384, 768, 384, dflag);

        // per-axis QKV (small L3-resident buffer) + attention into shared ATOc columns
        for (int i = 0; i < 3; ++i) {
            gemm_bt<0><<<dim3(Tc / 128, 9), 256, 0, stream>>>(Xc, qkvT + (size_t)(i * 1152) * 384,
                                                              QKVc, nullptr, nullptr, Tc, 1152, 384);
            if (i == 0)      attn3     <<<NB * 12, 256, 0, stream>>>(QKVc, ATOc,              1152, 1152);
            else if (i == 1) attn16_lds<<<NB * 48, 768, 0, stream>>>(QKVc, ATOc + 384, 16, 1, 1152, 1152);
            else             attn16_lds<<<NB * 48, 768, 0, stream>>>(QKVc, ATOc + 768, 1, 16, 1152, 1152);
        }

        // fused O-projection: sum over 3 axes in one K=1152 GEMM (+ Sum(bo) + residual Xc)
        gemm_bt<1><<<dim3(Tc / 128, 3), 256, 0, stream>>>(ATOc, woTf, ABc, vboS, Xc, Tc, 384, 1152);

        ln_kernel<<<Tc / 4, 256, 0, stream>>>(ABc, T1c, vg1, vbe1, Tc);
        gemm256<2><<<dim3(Tc / 256, 6), 512, 0, stream>>>(T1c, w1mT, BIGc, vb1m, Tc, 1536, 384);
        gemm_bt<1><<<dim3(Tc / 128, 3), 256, 0, stream>>>(BIGc, w2mT, ABc, vb2m, T1c, Tc, 384, 1536);
        // fused LN2 + transpose straight to d_out (saves the Xc round-trip)
        ln_transpose_out<<<dim3(24, NB), 256, 0, stream>>>(ABc, d_out, xoff, vg2, vbe2, dflag);
    }
}

// Round 23
// 1398.138 us; speedup vs baseline: 1.0915x; 1.0215x over previous
//
#include <hip/hip_runtime.h>

typedef unsigned short u16;
typedef __bf16 bf16;
typedef bf16  bf16x4 __attribute__((ext_vector_type(4)));
typedef bf16  bf16x8 __attribute__((ext_vector_type(8)));
typedef float f32x4  __attribute__((ext_vector_type(4)));

__device__ __forceinline__ u16  f2b(float v) { return __builtin_bit_cast(u16, (bf16)v); }
__device__ __forceinline__ float b2f(u16 b)  { return (float)__builtin_bit_cast(bf16, b); }

// ---------------- dtype probe: flag=1 if float inputs are f32, 0 if bf16 ----------------
__global__ void probe_dtype(const float* xf, int* flag) {
    __shared__ int cnt[256];
    const int tid = threadIdx.x;
    int good = 0;
#pragma unroll
    for (int i = 0; i < 4; ++i) {
        const float a = fabsf(xf[tid * 4 + i]);
        if (a > 9.5e-7f && a < 1.0e6f) good++;   // NaN fails both
    }
    cnt[tid] = good;
    __syncthreads();
    if (tid == 0) { int s = 0; for (int i = 0; i < 256; ++i) s += cnt[i]; *flag = (s > 512) ? 1 : 0; }
}

__device__ __forceinline__ float rd_flag(const void* p, int i, int f32) {
    return f32 ? ((const float*)p)[i] : b2f(((const u16*)p)[i]);
}

// ======== consolidated small-vector conversion (PROVEN R21) ========
__global__ __launch_bounds__(256)
void cvt_all(const void* bo0, const void* bo1, const void* bo2,
             const void* g1, const void* be1, const void* g2, const void* be2,
             const void* b1m, const void* b2m, bf16* vp, const int* flag)
{
    const int f32 = *flag;
    const int i = blockIdx.x * 256 + threadIdx.x;   // 15 blocks x 256 = 3840
    if (i < 384) {
        vp[i] = (bf16)(rd_flag(bo0, i, f32) + rd_flag(bo1, i, f32) + rd_flag(bo2, i, f32));
    } else if (i < 768)  { vp[i] = (bf16)rd_flag(g1,  i - 384,  f32); }
    else if (i < 1152)   { vp[i] = (bf16)rd_flag(be1, i - 768,  f32); }
    else if (i < 1536)   { vp[i] = (bf16)rd_flag(g2,  i - 1152, f32); }
    else if (i < 1920)   { vp[i] = (bf16)rd_flag(be2, i - 1536, f32); }
    else if (i < 3456)   { vp[i] = (bf16)rd_flag(b1m, i - 1920, f32); }
    else                 { vp[i] = (bf16)rd_flag(b2m, i - 3456, f32); }
}

// ======== consolidated weight transposes (PROVEN R21) ========
struct SrcPtrs { const void* p[11]; };
__global__ __launch_bounds__(256)
void wtrans_all(SrcPtrs srcs, u16* wsbase, const int* flag)
{
    const int prefix[12] = {0, 144, 432, 576, 720, 1008, 1152, 1296, 1584, 1728, 2304, 2880};
    const int Carr[11]   = {384, 768, 384,  384, 768, 384,  384, 768, 384,  1536, 384};
    const int OSarr[11]  = {384, 384, 1152, 384, 384, 1152, 384, 384, 1152, 384, 1536};
    const int DOarr[11]  = {0, 147456, 1327104, 442368, 589824, 1327488,
                            884736, 1032192, 1327872, 1769472, 2359296};

    __shared__ u16 tile[32][34];
    const int f32 = *flag;
    const int bid = blockIdx.x;
    int s = 0;
#pragma unroll
    for (int k = 0; k < 11; ++k) if (bid >= prefix[k + 1]) s = k + 1;
    const int tix = bid - prefix[s];
    const int C = Carr[s], ostride = OSarr[s];
    const int tilesX = C >> 5;
    const int c0 = (tix % tilesX) * 32, r0 = (tix / tilesX) * 32;
    const void* in = srcs.p[s];
    u16* out = wsbase + DOarr[s];

    const int tx = threadIdx.x & 31, ty = threadIdx.x >> 5;   // 32 x 8
#pragma unroll
    for (int i = 0; i < 4; ++i) {
        const int idx = (r0 + ty + i * 8) * C + c0 + tx;
        tile[ty + i * 8][tx] = f32 ? f2b(((const float*)in)[idx]) : ((const u16*)in)[idx];
    }
    __syncthreads();
#pragma unroll
    for (int i = 0; i < 4; ++i)
        out[(size_t)(c0 + ty + i * 8) * ostride + r0 + tx] = tile[tx][ty + i * 8];
}

// ---- transpose + convert: in[z][R][C] (flag dtype) -> out[z][C][ostride] bf16 (input x) ----
__global__ void transpose_cvt(const void* in, u16* out, size_t base_off, int R, int C, int ostride, const int* flag) {
    __shared__ u16 tile[32][34];
    const int f32 = *flag;
    const int c0 = blockIdx.x * 32, r0 = blockIdx.y * 32;
    const size_t bi = base_off + (size_t)blockIdx.z * R * C;
    const size_t bo = (size_t)blockIdx.z * C * ostride;
    const int tx = threadIdx.x, ty = threadIdx.y;
#pragma unroll
    for (int i = 0; i < 4; ++i) {
        const size_t idx = bi + (size_t)(r0 + ty + i * 8) * C + c0 + tx;
        tile[ty + i * 8][tx] = f32 ? f2b(((const float*)in)[idx]) : ((const u16*)in)[idx];
    }
    __syncthreads();
#pragma unroll
    for (int i = 0; i < 4; ++i)
        out[bo + (size_t)(c0 + ty + i * 8) * ostride + r0 + tx] = tile[tx][ty + i * 8];
}

// ---------------- global -> LDS async staging (16B/lane) ----------------
__device__ __forceinline__ void gld_lds16(const bf16* g, bf16* l) {
    __builtin_amdgcn_global_load_lds((__attribute__((address_space(1))) void*)g,
                                     (__attribute__((address_space(3))) void*)l,
                                     16, 0, 0);
}

// ---------------- GEMM 256x256, 8 waves, 2-phase dbuf, swizzled LDS (PROVEN R5-R22) ----------------
// MODE 0: C = acc ; MODE 2: C = gelu(acc + bias[n])
template<int MODE>
__global__ __launch_bounds__(512)
void gemm256(const bf16* __restrict__ A, const bf16* __restrict__ BT,
             bf16* C, const bf16* __restrict__ bias, int M, int N, int K)
{
    __shared__ __align__(16) bf16 sm[65536];        // 128 KB
    const int tid = threadIdx.x;

    const int gx = gridDim.x, gy = gridDim.y;
    int lin = blockIdx.y * gx + blockIdx.x;
    const int nwg = gx * gy;
    const int q = nwg >> 3, r8 = nwg & 7;
    const int xcd = lin & 7, idx = lin >> 3;
    lin = (xcd < r8 ? xcd * (q + 1) : r8 * (q + 1) + (xcd - r8) * q) + idx;
    const int bm0 = (lin / gy) * 256;
    const int bn0 = (lin % gy) * 256;

    const int lane = tid & 63, wid = tid >> 6;
    const int wr = wid >> 2, wc = wid & 3;           // 2x4 waves, wave tile 128x64
    const int fr = lane & 15, fg = lane >> 4;
    const int arow = tid >> 3;                       // 0..63
    const int scol = ((tid & 7) ^ (arow & 7)) << 3;  // pre-swizzled source col

    const bf16* Ab = A  + (size_t)(bm0 + arow) * K + scol;
    const bf16* Bb = BT + (size_t)(bn0 + arow) * K + scol;

    bf16* const lA0 = sm;
    bf16* const lA1 = sm + 16384;
    bf16* const lB0 = sm + 32768;
    bf16* const lB1 = sm + 49152;

    f32x4 acc[8][4] = {};
    const int NT = K >> 6;

#pragma unroll
    for (int i = 0; i < 4; ++i) gld_lds16(Ab + (size_t)i * 64 * K, lA0 + i * 4096 + tid * 8);
#pragma unroll
    for (int i = 0; i < 4; ++i) gld_lds16(Bb + (size_t)i * 64 * K, lB0 + i * 4096 + tid * 8);
    __syncthreads();

    const int sw = fr & 7;
    for (int t = 0; t < NT; ++t) {
        if (t + 1 < NT) {
            const int k0 = (t + 1) << 6;
            bf16* la = ((t + 1) & 1) ? lA1 : lA0;
            bf16* lb = ((t + 1) & 1) ? lB1 : lB0;
#pragma unroll
            for (int i = 0; i < 4; ++i) gld_lds16(Ab + k0 + (size_t)i * 64 * K, la + i * 4096 + tid * 8);
#pragma unroll
            for (int i = 0; i < 4; ++i) gld_lds16(Bb + k0 + (size_t)i * 64 * K, lb + i * 4096 + tid * 8);
        }
        const bf16* la = (t & 1) ? lA1 : lA0;
        const bf16* lb = (t & 1) ? lB1 : lB0;
#pragma unroll
        for (int kk = 0; kk < 2; ++kk) {
            const int so = ((((kk << 2) + fg) ^ sw) << 3);
            bf16x8 bfv[4];
#pragma unroll
            for (int n = 0; n < 4; ++n)
                bfv[n] = *(const bf16x8*)&lb[(wc * 64 + n * 16 + fr) * 64 + so];
#pragma unroll
            for (int m = 0; m < 8; ++m) {
                const bf16x8 af = *(const bf16x8*)&la[(wr * 128 + m * 16 + fr) * 64 + so];
#pragma unroll
                for (int n = 0; n < 4; ++n)
                    acc[m][n] = __builtin_amdgcn_mfma_f32_16x16x32_bf16(af, bfv[n], acc[m][n], 0, 0, 0);
            }
        }
        __syncthreads();
    }

    // epilogue: acc (+bias/gelu) -> LDS bf16 [256][256] -> coalesced 16B stores
#pragma unroll
    for (int n = 0; n < 4; ++n) {
        const int col = wc * 64 + n * 16 + fr;
        const float bv = (MODE == 2) ? (float)bias[bn0 + col] : 0.f;
#pragma unroll
        for (int m = 0; m < 8; ++m) {
            const int row0 = wr * 128 + m * 16 + fg * 4;
#pragma unroll
            for (int r = 0; r < 4; ++r) {
                float v = acc[m][n][r];
                if (MODE == 2) { v += bv; v = 0.5f * v * (1.f + erff(v * 0.70710678118654752f)); }
                sm[(row0 + r) * 256 + col] = (bf16)v;
            }
        }
    }
    __syncthreads();
#pragma unroll
    for (int it = 0; it < 16; ++it) {
        const int chunk = it * 512 + tid;
        const int row = chunk >> 5, c8 = (chunk & 31) << 3;
        *(bf16x8*)&C[(size_t)(bm0 + row) * N + bn0 + c8] = *(const bf16x8*)&sm[row * 256 + c8];
    }
}

// ======== GEMM 128x128: SINGLE-buffer m97 2-barrier loop, 32KB LDS (PROVEN R13-R22) ========
// MODE 0: C = acc ; MODE 1: C = acc + bias[n] + add[m,n]
// zA/zB/zC: per-blockIdx.z element strides for batched dispatch (0 for unbatched)
template<int MODE>
__global__ __launch_bounds__(256)
void gemm_bt(const bf16* __restrict__ A, const bf16* __restrict__ BT,
             bf16* C, const bf16* __restrict__ bias,
             const bf16* add, int M, int N, int K,
             size_t zA, size_t zB, size_t zC)
{
    __shared__ __align__(16) bf16 sm[16384];         // 32 KB: stage A(16KB)+B(16KB); epi: f32 64x128
    const int tid = threadIdx.x;

    const int gx = gridDim.x, gy = gridDim.y;
    int lin = blockIdx.y * gx + blockIdx.x;
    const int nwg = gx * gy;
    const int q = nwg >> 3, r8 = nwg & 7;
    const int xcd = lin & 7, idx = lin >> 3;
    lin = (xcd < r8 ? xcd * (q + 1) : r8 * (q + 1) + (xcd - r8) * q) + idx;
    const int bm0 = (lin / gy) * 128;
    const int bn0 = (lin % gy) * 128;

    A  += (size_t)blockIdx.z * zA;
    BT += (size_t)blockIdx.z * zB;
    C  += (size_t)blockIdx.z * zC;

    const int lane = tid & 63, wid = tid >> 6;
    const int wr = wid >> 1, wc = wid & 1;           // 2x2 waves, wave tile 64x64
    const int fr = lane & 15, fg = lane >> 4;
    const int arow = tid >> 3;                       // 0..31
    const int scol = ((tid & 7) ^ (arow & 7)) << 3;

    const bf16* Ab = A  + (size_t)(bm0 + arow) * K + scol;
    const bf16* Bb = BT + (size_t)(bn0 + arow) * K + scol;

    bf16* const lA = sm;                             // 128x64
    bf16* const lB = sm + 8192;

    f32x4 acc[4][4] = {};
    const int NT = K >> 6;
    const int sw = fr & 7;

    for (int t = 0; t < NT; ++t) {
        __syncthreads();                             // WAR: previous compute reads retired
        const int k0 = t << 6;
#pragma unroll
        for (int i = 0; i < 4; ++i) gld_lds16(Ab + k0 + (size_t)i * 32 * K, lA + i * 2048 + tid * 8);
#pragma unroll
        for (int i = 0; i < 4; ++i) gld_lds16(Bb + k0 + (size_t)i * 32 * K, lB + i * 2048 + tid * 8);
        __syncthreads();                             // RAW: vmcnt drained, stage visible
#pragma unroll
        for (int kk = 0; kk < 2; ++kk) {
            bf16x8 af[4], bfv[4];
#pragma unroll
            for (int m = 0; m < 4; ++m)
                af[m] = *(const bf16x8*)&lA[(wr * 64 + m * 16 + fr) * 64 + ((((kk << 2) + fg) ^ sw) << 3)];
#pragma unroll
            for (int n = 0; n < 4; ++n)
                bfv[n] = *(const bf16x8*)&lB[(wc * 64 + n * 16 + fr) * 64 + ((((kk << 2) + fg) ^ sw) << 3)];
#pragma unroll
            for (int m = 0; m < 4; ++m)
#pragma unroll
                for (int n = 0; n < 4; ++n)
                    acc[m][n] = __builtin_amdgcn_mfma_f32_16x16x32_bf16(af[m], bfv[n], acc[m][n], 0, 0, 0);
        }
    }
    __syncthreads();                                 // all compute reads done before epi reuse

    // ---- epilogue: two 64-row halves via f32 [64][128] tile, barriered ----
    float* lc = (float*)sm;
#pragma unroll
    for (int half = 0; half < 2; ++half) {
        if (wr == half) {                            // wave-uniform branch
#pragma unroll
            for (int n = 0; n < 4; ++n) {
                const int col = wc * 64 + n * 16 + fr;
#pragma unroll
                for (int m = 0; m < 4; ++m)
#pragma unroll
                    for (int r2 = 0; r2 < 4; ++r2)
                        lc[(m * 16 + fg * 4 + r2) * 128 + col] = acc[m][n][r2];
            }
        }
        __syncthreads();                             // stores visible to all waves
#pragma unroll
        for (int i = 0; i < 8; ++i) {
            const int chunk = i * 256 + tid;         // 2048 chunks = 64x128 / 4
            const int row = chunk >> 5, cb = (chunk & 31) * 4;
            const size_t goff = (size_t)(bm0 + half * 64 + row) * N + bn0 + cb;
            const f32x4 v = ((const f32x4*)lc)[chunk];
            bf16x4 o;
            if (MODE == 1) {
                const bf16x4 bv = *(const bf16x4*)&bias[bn0 + cb];
                const bf16x4 av = *(const bf16x4*)&add[goff];
#pragma unroll
                for (int e = 0; e < 4; ++e) o[e] = (bf16)(v[e] + (float)bv[e] + (float)av[e]);
            } else {
#pragma unroll
                for (int e = 0; e < 4; ++e) o[e] = (bf16)v[e];
            }
            *(bf16x4*)&C[goff] = o;
        }
        __syncthreads();                             // reads done before next half overwrites
    }
}

// ==== attention T=16, LDS-staged, BOTH axes in one dispatch (math = PROVEN R22 attn16_lds) ====
// blockIdx.y = 0 -> axis1 (tstride 16, lastmul 1), 1 -> axis2 (tstride 1, lastmul 16)
__global__ __launch_bounds__(768)
void attn16_lds2(const bf16* __restrict__ QKV3, bf16* __restrict__ O, size_t qkvz, int qs, int os)
{
    __shared__ bf16 kv[16 * 1160];                  // 16 tokens x 1152 (+8 pad) = 36.25 KB
    const int axis = blockIdx.y;                    // 0 or 1
    const int tstride = axis ? 1 : 16;
    const int lastmul = axis ? 16 : 1;
    const bf16* QKV = QKV3 + (size_t)(axis + 1) * qkvz;
    bf16* Oc = O + 384 * (axis + 1);

    const int tid  = threadIdx.x;
    const int lane = tid & 63, h = tid >> 6;        // wave = head 0..11
    const int seq  = blockIdx.x;
    const int b    = seq / 48, r2 = seq % 48;
    const int s    = r2 >> 4, last = r2 & 15;
    const int tbase = b * 768 + s * 256 + last * lastmul;
    const int fr = lane & 15, fg = lane >> 4;

    // cooperative stage: 2304 bf16x8 chunks over 768 threads (3 each), coalesced rows
#pragma unroll
    for (int k = 0; k < 3; ++k) {
        const int c = k * 768 + tid;
        const int row = c / 144, col = (c % 144) * 8;
        *(bf16x8*)&kv[row * 1160 + col] =
            *(const bf16x8*)&QKV[(size_t)(tbase + row * tstride) * qs + col];
    }
    __syncthreads();

    const bf16* base = kv + h * 32;
    const bf16x8 qf = *(const bf16x8*)&base[fr * 1160 + fg * 8];
    const bf16x8 kf = *(const bf16x8*)&base[fr * 1160 + 384 + fg * 8];
    const f32x4 z = {0.f, 0.f, 0.f, 0.f};
    f32x4 S = __builtin_amdgcn_mfma_f32_16x16x32_bf16(kf, qf, z, 0, 0, 0);

    const float sc = 0.17677669529663687f;
    float mx = fmaxf(fmaxf(S[0], S[1]), fmaxf(S[2], S[3]));
    mx = fmaxf(mx, __shfl_xor(mx, 16));
    mx = fmaxf(mx, __shfl_xor(mx, 32));
    float p[4], sum = 0.f;
#pragma unroll
    for (int r = 0; r < 4; ++r) { p[r] = __expf((S[r] - mx) * sc); sum += p[r]; }
    sum += __shfl_xor(sum, 16);
    sum += __shfl_xor(sum, 32);
    const float inv = 1.f / sum;

    bf16x8 pa;
#pragma unroll
    for (int j = 0; j < 8; ++j) {
        const int srcg = 2 * fg + (j >> 2);
        const float v = __shfl(p[j & 3], fr + 16 * (srcg & 3));
        pa[j] = (bf16)(fg < 2 ? v * inv : 0.f);
    }

#pragma unroll
    for (int t = 0; t < 2; ++t) {
        bf16x8 vf;
#pragma unroll
        for (int j = 0; j < 8; ++j) {
            const int key = fg * 8 + j;                  // valid (<16) iff fg<2
            vf[j] = (fg < 2) ? base[key * 1160 + 768 + fr + 16 * t] : (bf16)0.f;
        }
        f32x4 o = __builtin_amdgcn_mfma_f32_16x16x32_bf16(pa, vf, z, 0, 0, 0);
#pragma unroll
        for (int r = 0; r < 4; ++r)
            Oc[(size_t)(tbase + (fg * 4 + r) * tstride) * os + h * 32 + fr + 16 * t] = (bf16)o[r];
    }
}

// ---------------- attention, T=3: one thread per (seq, head) (PROVEN) ----------------
__global__ __launch_bounds__(256)
void attn3(const bf16* __restrict__ QKV, bf16* __restrict__ O, int qs, int os)
{
    const int t    = blockIdx.x * 256 + threadIdx.x;
    const int head = t % 12;
    const int seq  = t / 12;
    const int b    = seq >> 8, hw = seq & 255;
    const size_t base  = (size_t)(b * 768 + hw) * qs + head * 32;
    const size_t tstep = (size_t)256 * qs;

    float s[3][3] = {};
#pragma unroll
    for (int c = 0; c < 4; ++c) {
        bf16x8 q[3], k[3];
#pragma unroll
        for (int i = 0; i < 3; ++i) {
            q[i] = *(const bf16x8*)(QKV + base + i * tstep + c * 8);
            k[i] = *(const bf16x8*)(QKV + base + i * tstep + 384 + c * 8);
        }
#pragma unroll
        for (int i = 0; i < 3; ++i)
#pragma unroll
            for (int j = 0; j < 3; ++j) {
                float a = 0.f;
#pragma unroll
                for (int e = 0; e < 8; ++e) a += (float)q[i][e] * (float)k[j][e];
                s[i][j] += a;
            }
    }
    const float sc = 0.17677669529663687f;
    float p[3][3];
#pragma unroll
    for (int i = 0; i < 3; ++i) {
        const float mx = fmaxf(s[i][0], fmaxf(s[i][1], s[i][2]));
        float sum = 0.f;
#pragma unroll
        for (int j = 0; j < 3; ++j) { p[i][j] = __expf((s[i][j] - mx) * sc); sum += p[i][j]; }
        const float inv = 1.f / sum;
#pragma unroll
        for (int j = 0; j < 3; ++j) p[i][j] *= inv;
    }
    const size_t obase = (size_t)(b * 768 + hw) * os + head * 32;
#pragma unroll
    for (int c = 0; c < 4; ++c) {
        bf16x8 v[3];
#pragma unroll
        for (int j = 0; j < 3; ++j) v[j] = *(const bf16x8*)(QKV + base + j * tstep + 768 + c * 8);
#pragma unroll
        for (int i = 0; i < 3; ++i) {
            bf16x8 ov;
#pragma unroll
            for (int e = 0; e < 8; ++e)
                ov[e] = (bf16)(p[i][0] * (float)v[0][e] + p[i][1] * (float)v[1][e] + p[i][2] * (float)v[2][e]);
            *(bf16x8*)(O + obase + (size_t)i * 256 * os + c * 8) = ov;
        }
    }
}

// ---------------- LayerNorm over 384, one wave per token (LN1) ----------------
__global__ __launch_bounds__(256)
void ln_kernel(const bf16* __restrict__ in, bf16* __restrict__ out,
               const bf16* __restrict__ g, const bf16* __restrict__ be, int ntok)
{
    const int w    = (blockIdx.x * 256 + threadIdx.x) >> 6;
    const int lane = threadIdx.x & 63;
    if (w >= ntok) return;
    const bf16* row = in + (size_t)w * 384;
    float x[6], sum = 0.f;
#pragma unroll
    for (int i = 0; i < 6; ++i) { x[i] = (float)row[lane + i * 64]; sum += x[i]; }
#pragma unroll
    for (int o = 32; o >= 1; o >>= 1) sum += __shfl_xor(sum, o);
    const float mu = sum * (1.f / 384.f);
    float vs = 0.f;
#pragma unroll
    for (int i = 0; i < 6; ++i) { const float d = x[i] - mu; vs += d * d; }
#pragma unroll
    for (int o = 32; o >= 1; o >>= 1) vs += __shfl_xor(vs, o);
    const float rstd = rsqrtf(vs * (1.f / 384.f) + 1e-5f);
    bf16* orow = out + (size_t)w * 384;
#pragma unroll
    for (int i = 0; i < 6; ++i)
        orow[lane + i * 64] = (bf16)((x[i] - mu) * rstd * (float)g[lane + i * 64] + (float)be[lane + i * 64]);
}

// ======== fused LN2 + output transpose (PROVEN R20-R22) ========
__global__ __launch_bounds__(256)
void ln_transpose_out(const bf16* __restrict__ in, void* out, size_t base_off,
                      const bf16* __restrict__ g, const bf16* __restrict__ be, const int* flag)
{
    __shared__ bf16 tile[32][388];                  // pad 388 -> 2-way bank conflict (free)
    const int f32 = *flag;
    const int tid = threadIdx.x;
    const int lane = tid & 63, w = tid >> 6;        // wave 0..3
    const int r0 = blockIdx.x * 32;                 // token window within batch image
    const int zz = blockIdx.y;
    const bf16* inz = in + ((size_t)zz * 768 + r0) * 384;

#pragma unroll
    for (int p = 0; p < 8; ++p) {                   // 8 passes x 4 waves = 32 tokens
        const int tok = p * 4 + w;
        const bf16* row = inz + (size_t)tok * 384;
        float x[6], sum = 0.f;
#pragma unroll
        for (int i = 0; i < 6; ++i) { x[i] = (float)row[lane + i * 64]; sum += x[i]; }
#pragma unroll
        for (int o = 32; o >= 1; o >>= 1) sum += __shfl_xor(sum, o);
        const float mu = sum * (1.f / 384.f);
        float vs = 0.f;
#pragma unroll
        for (int i = 0; i < 6; ++i) { const float d = x[i] - mu; vs += d * d; }
#pragma unroll
        for (int o = 32; o >= 1; o >>= 1) vs += __shfl_xor(vs, o);
        const float rstd = rsqrtf(vs * (1.f / 384.f) + 1e-5f);
#pragma unroll
        for (int i = 0; i < 6; ++i)
            tile[tok][lane + i * 64] =
                (bf16)((x[i] - mu) * rstd * (float)g[lane + i * 64] + (float)be[lane + i * 64]);
    }
    __syncthreads();

    // transposed write: out[z][c][768], cols r0..r0+31
    const size_t bo = base_off + (size_t)zz * 384 * 768;
#pragma unroll
    for (int it = 0; it < 48; ++it) {               // 384*32 / 256
        const int idx = it * 256 + tid;
        const int c = idx >> 5, r = idx & 31;
        const u16 v = __builtin_bit_cast(u16, tile[r][c]);
        const size_t o = bo + (size_t)c * 768 + r0 + r;
        if (f32) ((float*)out)[o] = b2f(v); else ((u16*)out)[o] = v;
    }
}

// ---------------- launch ----------------
extern "C" void kernel_launch(void* const* d_in, const int* in_sizes, int n_in,
                              void* d_out, int out_size, void* d_ws, size_t ws_size,
                              hipStream_t stream)
{
    const void* x = d_in[0];
    const void *Wq[3], *Wkv[3], *Wo[3], *bo[3];
    for (int i = 0; i < 3; ++i) {
        Wq[i]  = d_in[1 + 4 * i];
        Wkv[i] = d_in[2 + 4 * i];
        Wo[i]  = d_in[3 + 4 * i];
        bo[i]  = d_in[4 + 4 * i];
    }
    const void* g1  = d_in[13];
    const void* be1 = d_in[14];
    const void* W1m = d_in[15];
    const void* b1m = d_in[16];
    const void* W2m = d_in[17];
    const void* b2m = d_in[18];
    const void* g2  = d_in[19];
    const void* be2 = d_in[20];

    // ---- workspace layout (element offsets match wtrans_all's DOarr) ----
    char* ws = (char*)d_ws;
    bf16* qkvT = (bf16*)(ws);                       // [3456][384] per-axis QKV weights (i*1152 rows)
    bf16* woTf = (bf16*)(ws + 2654208ull);          // [384][1152] stacked O-proj weights
    bf16* w1mT = (bf16*)(ws + 3538944ull);          // [1536][384]
    bf16* w2mT = (bf16*)(ws + 4718592ull);          // [384][1536]
    bf16* vp   = (bf16*)(ws + 5898240ull);          // 3840 bf16: vboS,vg1,vbe1,vg2,vbe2,vb1m,vb2m
    bf16* vboS = vp;
    bf16* vg1  = vp + 384;  bf16* vbe1 = vp + 768;
    bf16* vg2  = vp + 1152; bf16* vbe2 = vp + 1536;
    bf16* vb1m = vp + 1920; bf16* vb2m = vp + 3456;
    int* dflag = (int*)(ws + 5909504ull);
    const size_t WB = 6553600ull;                   // chunk region base

    // chunk size: NB=32 (4 chunks); attn-phase live set ~227MB -> L3-resident
    int NB = 32;
    while (NB > 2) {
        size_t need = WB + (size_t)NB * 768 * (3 * 384 + 4 * 1152 + 1536) * 2;
        if (need <= ws_size) break;
        NB >>= 1;
    }
    const int Tc = NB * 768;
    const size_t tokB = (size_t)Tc * 384 * 2;
    bf16* Xc    = (bf16*)(ws + WB);
    bf16* ABc   = (bf16*)(ws + WB + tokB);
    bf16* T1c   = (bf16*)(ws + WB + 2 * tokB);
    bf16* ATOc  = (bf16*)(ws + WB + 3 * tokB);      // Tc x 1152 (3 axes side by side)
    bf16* QKV3c = (bf16*)(ws + WB + 6 * tokB);      // 3 x (Tc x 1152), one slab per axis
    bf16* BIGc  = (bf16*)(ws + WB + 15 * tokB);     // Tc x 1536 (MLP hidden)
    const size_t qkvz = (size_t)Tc * 1152;          // per-axis QKV slab (elements)

    // ---- consolidated setup: probe + 1 vector-cvt + 1 batched weight transpose ----
    probe_dtype<<<1, 256, 0, stream>>>((const float*)x, dflag);
    cvt_all<<<15, 256, 0, stream>>>(bo[0], bo[1], bo[2], g1, be1, g2, be2, b1m, b2m, vp, dflag);
    SrcPtrs sp;
    sp.p[0] = Wq[0]; sp.p[1] = Wkv[0]; sp.p[2] = Wo[0];
    sp.p[3] = Wq[1]; sp.p[4] = Wkv[1]; sp.p[5] = Wo[1];
    sp.p[6] = Wq[2]; sp.p[7] = Wkv[2]; sp.p[8] = Wo[2];
    sp.p[9] = W1m;   sp.p[10] = W2m;
    wtrans_all<<<2880, 256, 0, stream>>>(sp, (u16*)ws, dflag);

    const dim3 tb(32, 8);
    for (int b0 = 0; b0 < 128; b0 += NB) {
        const size_t xoff = (size_t)b0 * 384 * 768;
        transpose_cvt<<<dim3(24, 12, NB), tb, 0, stream>>>(x, (u16*)Xc, xoff, 384, 768, 384, dflag);

        // ALL 3 axes' QKV in one batched GEMM dispatch (z = axis)
        gemm_bt<0><<<dim3(Tc / 128, 9, 3), 256, 0, stream>>>(
            Xc, qkvT, QKV3c, nullptr, nullptr, Tc, 1152, 384,
            0, (size_t)1152 * 384, qkvz);

        // attention: axis0 (T=3) + axes 1,2 (T=16) in one merged dispatch
        attn3<<<NB * 12, 256, 0, stream>>>(QKV3c, ATOc, 1152, 1152);
        attn16_lds2<<<dim3(NB * 48, 2), 768, 0, stream>>>(QKV3c, ATOc, qkvz, 1152, 1152);

        // fused O-projection: sum over 3 axes in one K=1152 GEMM (+ Sum(bo) + residual Xc)
        gemm_bt<1><<<dim3(Tc / 128, 3), 256, 0, stream>>>(ATOc, woTf, ABc, vboS, Xc, Tc, 384, 1152, 0, 0, 0);

        ln_kernel<<<Tc / 4, 256, 0, stream>>>(ABc, T1c, vg1, vbe1, Tc);
        gemm256<2><<<dim3(Tc / 256, 6), 512, 0, stream>>>(T1c, w1mT, BIGc, vb1m, Tc, 1536, 384);
        gemm_bt<1><<<dim3(Tc / 128, 3), 256, 0, stream>>>(BIGc, w2mT, ABc, vb2m, T1c, Tc, 384, 1536, 0, 0, 0);
        // fused LN2 + transpose straight to d_out (saves the Xc round-trip)
        ln_transpose_out<<<dim3(24, NB), 256, 0, stream>>>(ABc, d_out, xoff, vg2, vbe2, dflag);
    }
}